// Round 1
// baseline (11401.875 us; speedup 1.0000x reference)
//
#include <hip/hip_runtime.h>

#define NR 4096
#define DD 2048
#define HH 2048
#define FF 512
#define VNUM 3

#define BM 128
#define BN 128
#define BK 16
#define PAD 4

// ---------------------------------------------------------------------------
// Tiled fp32 GEMM.  C[M,N] = A[M,K] @ B  (NT=1: B is [N,K] row-major, used as B^T)
// EMA=1: effective B = m*B + (1-m)*B2   (m read from device scalar `mom`)
// EPI: 0 = none, 1 = +bias, relu, 2 = +bias
// ---------------------------------------------------------------------------
template<int EMA, int EPI, int NT>
__global__ __launch_bounds__(256) void sgemm(
    const float* __restrict__ A, const float* __restrict__ B,
    const float* __restrict__ B2, const float* __restrict__ mom,
    const float* __restrict__ bias, float* __restrict__ C,
    int M, int N, int K)
{
    __shared__ float As[BK][BM + PAD];
    __shared__ float Bs[BK][BN + PAD];
    const int tid = threadIdx.x;
    const int bm = blockIdx.y * BM;
    const int bn = blockIdx.x * BN;
    const int tx = (tid & 15) << 3;
    const int ty = (tid >> 4) << 3;
    float acc[8][8];
#pragma unroll
    for (int i = 0; i < 8; ++i)
#pragma unroll
        for (int j = 0; j < 8; ++j) acc[i][j] = 0.f;

    float mv = 0.f, mv1 = 0.f;
    if (EMA) { mv = mom[0]; mv1 = 1.f - mv; }

    for (int k0 = 0; k0 < K; k0 += BK) {
        // A tile: BM x BK, stored transposed As[k][m]
#pragma unroll
        for (int u = 0; u < 2; ++u) {
            int q = u * 256 + tid;
            int r = q >> 2;
            int c = (q & 3) << 2;
            float4 av = *(const float4*)(A + (size_t)(bm + r) * K + k0 + c);
            As[c + 0][r] = av.x; As[c + 1][r] = av.y;
            As[c + 2][r] = av.z; As[c + 3][r] = av.w;
        }
        // B tile
#pragma unroll
        for (int u = 0; u < 2; ++u) {
            int q = u * 256 + tid;
            if (NT) {
                int r = q >> 2;            // row in [0,BN)
                int c = (q & 3) << 2;      // k in [0,BK)
                float4 bv = *(const float4*)(B + (size_t)(bn + r) * K + k0 + c);
                Bs[c + 0][r] = bv.x; Bs[c + 1][r] = bv.y;
                Bs[c + 2][r] = bv.z; Bs[c + 3][r] = bv.w;
            } else {
                int r = q >> 5;            // k in [0,BK)
                int c = (q & 31) << 2;     // col in [0,BN)
                size_t gi = (size_t)(k0 + r) * N + bn + c;
                float4 bv = *(const float4*)(B + gi);
                if (EMA) {
                    float4 b2 = *(const float4*)(B2 + gi);
                    bv.x = mv * bv.x + mv1 * b2.x;
                    bv.y = mv * bv.y + mv1 * b2.y;
                    bv.z = mv * bv.z + mv1 * b2.z;
                    bv.w = mv * bv.w + mv1 * b2.w;
                }
                *(float4*)&Bs[r][c] = bv;
            }
        }
        __syncthreads();
#pragma unroll
        for (int k = 0; k < BK; ++k) {
            float a[8], b[8];
#pragma unroll
            for (int i = 0; i < 8; ++i) a[i] = As[k][ty + i];
#pragma unroll
            for (int j = 0; j < 8; ++j) b[j] = Bs[k][tx + j];
#pragma unroll
            for (int i = 0; i < 8; ++i)
#pragma unroll
                for (int j = 0; j < 8; ++j) acc[i][j] = fmaf(a[i], b[j], acc[i][j]);
        }
        __syncthreads();
    }
#pragma unroll
    for (int i = 0; i < 8; ++i) {
#pragma unroll
        for (int jq = 0; jq < 2; ++jq) {
            float4 v = make_float4(acc[i][jq*4+0], acc[i][jq*4+1],
                                   acc[i][jq*4+2], acc[i][jq*4+3]);
            if (EPI) {
                float4 bb = *(const float4*)(bias + bn + tx + jq * 4);
                v.x += bb.x; v.y += bb.y; v.z += bb.z; v.w += bb.w;
                if (EPI == 1) {
                    v.x = fmaxf(v.x, 0.f); v.y = fmaxf(v.y, 0.f);
                    v.z = fmaxf(v.z, 0.f); v.w = fmaxf(v.w, 0.f);
                }
            }
            *(float4*)(C + (size_t)(bm + ty + i) * N + bn + tx + jq * 4) = v;
        }
    }
}

// ---------------------------------------------------------------------------
// BatchNorm (training mode): column stats over NR rows, then apply.
// ---------------------------------------------------------------------------
__global__ void bn_stats_partial(const float* __restrict__ X,
                                 float* __restrict__ psum, float* __restrict__ psq,
                                 int C)
{
    int c = blockIdx.x * 256 + threadIdx.x;
    int r0 = blockIdx.y * (NR / 32);
    float s = 0.f, q = 0.f;
    for (int r = r0; r < r0 + (NR / 32); ++r) {
        float v = X[(size_t)r * C + c];
        s += v;
        q = fmaf(v, v, q);
    }
    psum[(size_t)blockIdx.y * C + c] = s;
    psq [(size_t)blockIdx.y * C + c] = q;
}

__global__ void bn_finalize(const float* __restrict__ psum, const float* __restrict__ psq,
                            float* __restrict__ meanb, float* __restrict__ rstdb, int C)
{
    int c = blockIdx.x * 256 + threadIdx.x;
    float s = 0.f, q = 0.f;
    for (int u = 0; u < 32; ++u) {
        s += psum[(size_t)u * C + c];
        q += psq [(size_t)u * C + c];
    }
    float mn  = s * (1.0f / NR);
    float var = q * (1.0f / NR) - mn * mn;
    meanb[c] = mn;
    rstdb[c] = rsqrtf(var + 1e-5f);
}

// MODE 0: (x-m)*rstd ; MODE 1: relu(affine) ; MODE 2: relu(EMA-blended affine)
template<int MODE>
__global__ void bn_apply(float* __restrict__ X,
                         const float* __restrict__ meanb, const float* __restrict__ rstdb,
                         const float* __restrict__ ga, const float* __restrict__ ba,
                         const float* __restrict__ gb, const float* __restrict__ bb,
                         const float* __restrict__ mom, int total4, int C)
{
    float m = 0.f, m1 = 0.f;
    if (MODE == 2) { m = mom[0]; m1 = 1.f - m; }
    int stride = gridDim.x * blockDim.x;
    for (int t = blockIdx.x * blockDim.x + threadIdx.x; t < total4; t += stride) {
        int c = (t << 2) % C;
        float4 v  = ((float4*)X)[t];
        float4 mn = *(const float4*)(meanb + c);
        float4 rs = *(const float4*)(rstdb + c);
        v.x = (v.x - mn.x) * rs.x; v.y = (v.y - mn.y) * rs.y;
        v.z = (v.z - mn.z) * rs.z; v.w = (v.w - mn.w) * rs.w;
        if (MODE >= 1) {
            float4 gg  = *(const float4*)(ga + c);
            float4 bbv = *(const float4*)(ba + c);
            if (MODE == 2) {
                float4 g2 = *(const float4*)(gb + c);
                float4 b2 = *(const float4*)(bb + c);
                gg.x  = m*gg.x  + m1*g2.x; gg.y  = m*gg.y  + m1*g2.y;
                gg.z  = m*gg.z  + m1*g2.z; gg.w  = m*gg.w  + m1*g2.w;
                bbv.x = m*bbv.x + m1*b2.x; bbv.y = m*bbv.y + m1*b2.y;
                bbv.z = m*bbv.z + m1*b2.z; bbv.w = m*bbv.w + m1*b2.w;
            }
            v.x = fmaxf(fmaf(v.x, gg.x, bbv.x), 0.f);
            v.y = fmaxf(fmaf(v.y, gg.y, bbv.y), 0.f);
            v.z = fmaxf(fmaf(v.z, gg.z, bbv.z), 0.f);
            v.w = fmaxf(fmaf(v.w, gg.w, bbv.w), 0.f);
        }
        ((float4*)X)[t] = v;
    }
}

// ---------------------------------------------------------------------------
// Row-wise L2 normalize in place, rows of length FF=512. One wave per row.
// ---------------------------------------------------------------------------
__global__ void l2norm_rows(float* __restrict__ X)
{
    int row = blockIdx.x;
    int lane = threadIdx.x;  // 64
    float4* xr = (float4*)(X + (size_t)row * FF);
    float4 a = xr[lane];
    float4 b = xr[lane + 64];
    float ss = a.x*a.x + a.y*a.y + a.z*a.z + a.w*a.w
             + b.x*b.x + b.y*b.y + b.z*b.z + b.w*b.w;
#pragma unroll
    for (int o = 32; o > 0; o >>= 1) ss += __shfl_xor(ss, o);
    float sc = 1.f / fmaxf(sqrtf(ss), 1e-12f);
    a.x *= sc; a.y *= sc; a.z *= sc; a.w *= sc;
    b.x *= sc; b.y *= sc; b.z *= sc; b.w *= sc;
    xr[lane] = a;
    xr[lane + 64] = b;
}

// ---------------------------------------------------------------------------
// block reductions (256 threads = 4 waves)
// ---------------------------------------------------------------------------
__device__ __forceinline__ float block_sum(float v, float* sred)
{
#pragma unroll
    for (int o = 32; o > 0; o >>= 1) v += __shfl_xor(v, o);
    __syncthreads();
    if ((threadIdx.x & 63) == 0) sred[threadIdx.x >> 6] = v;
    __syncthreads();
    return sred[0] + sred[1] + sred[2] + sred[3];
}
__device__ __forceinline__ float block_max(float v, float* sred)
{
#pragma unroll
    for (int o = 32; o > 0; o >>= 1) v = fmaxf(v, __shfl_xor(v, o));
    __syncthreads();
    if ((threadIdx.x & 63) == 0) sred[threadIdx.x >> 6] = v;
    __syncthreads();
    return fmaxf(fmaxf(sred[0], sred[1]), fmaxf(sred[2], sred[3]));
}

// ---------------------------------------------------------------------------
// kernel_affinity row transform, in place over S = zk_n @ zk_n^T.
// S row i (dot products) -> mp row i; also writes rowsum_mp[i].
// ---------------------------------------------------------------------------
__global__ __launch_bounds__(256) void affinity_rows(float* __restrict__ S,
                                                     float* __restrict__ rowsum)
{
    const int i = blockIdx.x;
    const int tid = threadIdx.x;
    __shared__ float arow[NR];
    __shared__ float sred[4];
    __shared__ float svv[4];
    __shared__ int   sii[4];
    float* Srow = S + (size_t)i * NR;

    float s1 = 0.f;
    for (int j = tid; j < NR; j += 256) {
        float sij = Srow[j];
        float d = fmaxf(2.f - 2.f * sij, 0.f);
        float a = expf(-10.f * d);
        arow[j] = a;
        s1 += a;
    }
    __syncthreads();
    float S1 = block_sum(s1, sred);
    float invS1 = 1.f / S1;
    float Ad = arow[i] * invS1;       // diagonal of normalized A
    __syncthreads();                  // everyone read arow[i] before overwrite

    float s2 = 0.f;
    float bv = 3.4e38f; int bi = NR;
    for (int j = tid; j < NR; j += 256) {
        float Aj = arow[j] * invS1;
        arow[j] = Aj;                 // overwrite own slot with normalized A
        float diff = fabsf(Ad - Aj);
        float key = diff + (j == i ? 1.f : 0.f);
        if (key < bv) { bv = key; bi = j; }
        s2 += (j == i) ? 0.f : expf(Aj);
    }
    float S2 = block_sum(s2, sred);

    // argmin (value, first index) across block
#pragma unroll
    for (int o = 32; o > 0; o >>= 1) {
        float ov = __shfl_xor(bv, o);
        int   oi = __shfl_xor(bi, o);
        if (ov < bv || (ov == bv && oi < bi)) { bv = ov; bi = oi; }
    }
    __syncthreads();
    if ((tid & 63) == 0) { svv[tid >> 6] = bv; sii[tid >> 6] = bi; }
    __syncthreads();
    float fv = svv[0]; int idx = sii[0];
#pragma unroll
    for (int u = 1; u < 4; ++u)
        if (svv[u] < fv || (svv[u] == fv && sii[u] < idx)) { fv = svv[u]; idx = sii[u]; }

    float invS2 = 1.f / S2;
    float s3 = 0.f;
    for (int j = tid; j < NR; j += 256) {
        float Aj = arow[j];
        float diff = fabsf(Ad - Aj);
        float thr = (diff < 0.8f) ? 1.f : 0.f;
        float ind = ((j == idx) ? 1.f : 0.f) + ((j == i) ? 1.f : 0.f);
        float tk = thr * ind;
        float E = (j == i) ? 0.f : expf(Aj);
        float w = 1.f - E * invS2;
        float dyn = tk * w + (1.f - tk);
        float mv2 = Aj * dyn;
        Srow[j] = mv2;
        s3 += mv2;
    }
    float S3 = block_sum(s3, sred);
    if (tid == 0) rowsum[i] = S3;
}

// ---------------------------------------------------------------------------
// contrastive row: sim row (raw dots, x2 for /0.5 temp), log-softmax, weighted
// by mp row / rowsum; accumulate scalar into acc (fp64).
// ---------------------------------------------------------------------------
__global__ __launch_bounds__(256) void contrastive_rows(const float* __restrict__ Sim,
                                                        const float* __restrict__ MP,
                                                        const float* __restrict__ mprs,
                                                        double* __restrict__ acc)
{
    const int i = blockIdx.x;
    const int tid = threadIdx.x;
    __shared__ float srow[NR];
    __shared__ float sred[4];
    const float* simr = Sim + (size_t)i * NR;
    const float* mpr  = MP  + (size_t)i * NR;

    float mx = -3.4e38f;
    for (int j = tid; j < NR; j += 256) {
        float s = simr[j] * 2.f;
        srow[j] = s;
        mx = fmaxf(mx, s);
    }
    __syncthreads();
    float M = block_max(mx, sred);
    float se = 0.f;
    for (int j = tid; j < NR; j += 256) se += expf(srow[j] - M);
    float SE = block_sum(se, sred);
    float lse = M + logf(SE);
    float part = 0.f;
    for (int j = tid; j < NR; j += 256) part = fmaf(lse - srow[j], mpr[j], part);
    float P = block_sum(part, sred);
    if (tid == 0) atomicAdd(acc, (double)(P / mprs[i]));
}

__global__ void finalize_k(const double* __restrict__ acc, float* __restrict__ out)
{
    const double nn = (double)NR * (double)NR;
    out[0] = (float)(acc[0] / (3.0 * nn) + acc[1] / (6.0 * nn));
}

// ---------------------------------------------------------------------------
extern "C" void kernel_launch(void* const* d_in, const int* in_sizes, int n_in,
                              void* d_out, int out_size, void* d_ws, size_t ws_size,
                              hipStream_t stream)
{
    const float* x   = (const float*)d_in[0];
    const float* W1  = (const float*)d_in[1];
    const float* g1  = (const float*)d_in[2];
    const float* b1  = (const float*)d_in[3];
    const float* W2  = (const float*)d_in[4];
    const float* g2  = (const float*)d_in[5];
    const float* b2  = (const float*)d_in[6];
    const float* W3  = (const float*)d_in[7];
    const float* tW1 = (const float*)d_in[8];
    const float* tg1 = (const float*)d_in[9];
    const float* tb1 = (const float*)d_in[10];
    const float* tW2 = (const float*)d_in[11];
    const float* tg2 = (const float*)d_in[12];
    const float* tb2 = (const float*)d_in[13];
    const float* tW3 = (const float*)d_in[14];
    const float* dW1 = (const float*)d_in[15];
    const float* db1 = (const float*)d_in[16];
    const float* dW2 = (const float*)d_in[17];
    const float* db2 = (const float*)d_in[18];
    const float* mom = (const float*)d_in[19];
    float* out = (float*)d_out;

    float* ws = (float*)d_ws;
    size_t o = 0;
    float* h1 = ws + o;     o += (size_t)NR * HH;        // 8M
    float* h2 = ws + o;     o += (size_t)NR * HH;        // 8M (h1+h2 = NR*NR: sim alias)
    float* zq = ws + o;     o += (size_t)VNUM * NR * FF;
    float* zk = ws + o;     o += (size_t)VNUM * NR * FF;
    float* pp = ws + o;     o += (size_t)VNUM * NR * FF;
    float* mp = ws + o;     o += (size_t)NR * NR;
    float* rowsum = ws + o; o += NR;
    float* psum = ws + o;   o += 32 * HH;
    float* psq  = ws + o;   o += 32 * HH;
    float* meanb = ws + o;  o += HH;
    float* rstdb = ws + o;  o += HH;
    double* acc = (double*)(ws + o);                     // 2 doubles, 8B-aligned
    float* sim = h1;

    hipMemsetAsync(acc, 0, 2 * sizeof(double), stream);

    const dim3 TB(256);

    for (int v = 0; v < VNUM; ++v) {
        const float* xv  = x  + (size_t)v * NR * DD;
        float* zqv = zq + (size_t)v * NR * FF;
        float* zkv = zk + (size_t)v * NR * FF;
        float* pv  = pp + (size_t)v * NR * FF;
        const float* W1v  = W1  + (size_t)v * DD * HH;
        const float* W2v  = W2  + (size_t)v * HH * HH;
        const float* W3v  = W3  + (size_t)v * HH * FF;
        const float* tW1v = tW1 + (size_t)v * DD * HH;
        const float* tW2v = tW2 + (size_t)v * HH * HH;
        const float* tW3v = tW3 + (size_t)v * HH * FF;
        const float* g1v = g1 + (size_t)v * HH;  const float* b1v = b1 + (size_t)v * HH;
        const float* g2v = g2 + (size_t)v * HH;  const float* b2v = b2 + (size_t)v * HH;
        const float* tg1v = tg1 + (size_t)v * HH; const float* tb1v = tb1 + (size_t)v * HH;
        const float* tg2v = tg2 + (size_t)v * HH; const float* tb2v = tb2 + (size_t)v * HH;

        // ---- online fcn -> z_q[v] ----
        sgemm<0,0,0><<<dim3(HH/BN, NR/BM), TB, 0, stream>>>(xv, W1v, nullptr, nullptr, nullptr, h1, NR, HH, DD);
        bn_stats_partial<<<dim3(HH/256, 32), TB, 0, stream>>>(h1, psum, psq, HH);
        bn_finalize<<<dim3(HH/256), TB, 0, stream>>>(psum, psq, meanb, rstdb, HH);
        bn_apply<1><<<dim3(2048), TB, 0, stream>>>(h1, meanb, rstdb, g1v, b1v, nullptr, nullptr, nullptr, NR*HH/4, HH);

        sgemm<0,0,0><<<dim3(HH/BN, NR/BM), TB, 0, stream>>>(h1, W2v, nullptr, nullptr, nullptr, h2, NR, HH, HH);
        bn_stats_partial<<<dim3(HH/256, 32), TB, 0, stream>>>(h2, psum, psq, HH);
        bn_finalize<<<dim3(HH/256), TB, 0, stream>>>(psum, psq, meanb, rstdb, HH);
        bn_apply<1><<<dim3(2048), TB, 0, stream>>>(h2, meanb, rstdb, g2v, b2v, nullptr, nullptr, nullptr, NR*HH/4, HH);

        sgemm<0,0,0><<<dim3(FF/BN, NR/BM), TB, 0, stream>>>(h2, W3v, nullptr, nullptr, nullptr, zqv, NR, FF, HH);
        bn_stats_partial<<<dim3(FF/256, 32), TB, 0, stream>>>(zqv, psum, psq, FF);
        bn_finalize<<<dim3(FF/256), TB, 0, stream>>>(psum, psq, meanb, rstdb, FF);
        bn_apply<0><<<dim3(2048), TB, 0, stream>>>(zqv, meanb, rstdb, nullptr, nullptr, nullptr, nullptr, nullptr, NR*FF/4, FF);

        // ---- target fcn (EMA weights fused) -> z_k[v] ----
        sgemm<1,0,0><<<dim3(HH/BN, NR/BM), TB, 0, stream>>>(xv, tW1v, W1v, mom, nullptr, h1, NR, HH, DD);
        bn_stats_partial<<<dim3(HH/256, 32), TB, 0, stream>>>(h1, psum, psq, HH);
        bn_finalize<<<dim3(HH/256), TB, 0, stream>>>(psum, psq, meanb, rstdb, HH);
        bn_apply<2><<<dim3(2048), TB, 0, stream>>>(h1, meanb, rstdb, tg1v, tb1v, g1v, b1v, mom, NR*HH/4, HH);

        sgemm<1,0,0><<<dim3(HH/BN, NR/BM), TB, 0, stream>>>(h1, tW2v, W2v, mom, nullptr, h2, NR, HH, HH);
        bn_stats_partial<<<dim3(HH/256, 32), TB, 0, stream>>>(h2, psum, psq, HH);
        bn_finalize<<<dim3(HH/256), TB, 0, stream>>>(psum, psq, meanb, rstdb, HH);
        bn_apply<2><<<dim3(2048), TB, 0, stream>>>(h2, meanb, rstdb, tg2v, tb2v, g2v, b2v, mom, NR*HH/4, HH);

        sgemm<1,0,0><<<dim3(FF/BN, NR/BM), TB, 0, stream>>>(h2, tW3v, W3v, mom, nullptr, zkv, NR, FF, HH);
        bn_stats_partial<<<dim3(FF/256, 32), TB, 0, stream>>>(zkv, psum, psq, FF);
        bn_finalize<<<dim3(FF/256), TB, 0, stream>>>(psum, psq, meanb, rstdb, FF);
        bn_apply<0><<<dim3(2048), TB, 0, stream>>>(zkv, meanb, rstdb, nullptr, nullptr, nullptr, nullptr, nullptr, NR*FF/4, FF);

        // ---- mlp: p[v] = relu(z_q @ dW1 + db1) @ dW2 + db2 ----
        sgemm<0,1,0><<<dim3(HH/BN, NR/BM), TB, 0, stream>>>(zqv, dW1 + (size_t)v*FF*HH, nullptr, nullptr,
                                                            db1 + (size_t)v*HH, h1, NR, HH, FF);
        sgemm<0,2,0><<<dim3(FF/BN, NR/BM), TB, 0, stream>>>(h1, dW2 + (size_t)v*HH*FF, nullptr, nullptr,
                                                            db2 + (size_t)v*FF, pv, NR, FF, HH);

        // ---- normalize in place (z_q no longer needed raw) ----
        l2norm_rows<<<dim3(NR), dim3(64), 0, stream>>>(zqv);
        l2norm_rows<<<dim3(NR), dim3(64), 0, stream>>>(zkv);
        l2norm_rows<<<dim3(NR), dim3(64), 0, stream>>>(pv);
    }

    // inter pairs grouped by ki=v:  v=0:(q=1,q=2)  v=1:(0,2)  v=2:(0,1)
    const int QA[3] = {1, 0, 0};
    const int QB[3] = {2, 2, 1};
    for (int v = 0; v < VNUM; ++v) {
        float* zkv = zk + (size_t)v * NR * FF;
        float* zqv = zq + (size_t)v * NR * FF;

        sgemm<0,0,1><<<dim3(NR/BN, NR/BM), TB, 0, stream>>>(zkv, zkv, nullptr, nullptr, nullptr, mp, NR, NR, FF);
        affinity_rows<<<dim3(NR), TB, 0, stream>>>(mp, rowsum);

        sgemm<0,0,1><<<dim3(NR/BN, NR/BM), TB, 0, stream>>>(zqv, zkv, nullptr, nullptr, nullptr, sim, NR, NR, FF);
        contrastive_rows<<<dim3(NR), TB, 0, stream>>>(sim, mp, rowsum, acc + 0);

        float* pa = pp + (size_t)QA[v] * NR * FF;
        sgemm<0,0,1><<<dim3(NR/BN, NR/BM), TB, 0, stream>>>(pa, zkv, nullptr, nullptr, nullptr, sim, NR, NR, FF);
        contrastive_rows<<<dim3(NR), TB, 0, stream>>>(sim, mp, rowsum, acc + 1);

        float* pb = pp + (size_t)QB[v] * NR * FF;
        sgemm<0,0,1><<<dim3(NR/BN, NR/BM), TB, 0, stream>>>(pb, zkv, nullptr, nullptr, nullptr, sim, NR, NR, FF);
        contrastive_rows<<<dim3(NR), TB, 0, stream>>>(sim, mp, rowsum, acc + 1);
    }

    finalize_k<<<dim3(1), dim3(1), 0, stream>>>(acc, out);
}

// Round 3
// 4385.520 us; speedup vs baseline: 2.5999x; 2.5999x over previous
//
#include <hip/hip_runtime.h>

#define NR 4096
#define DD 2048
#define HH 2048
#define FF 512
#define VNUM 3

typedef unsigned short u16;
typedef __attribute__((ext_vector_type(8))) short short8;
typedef __attribute__((ext_vector_type(4))) float f32x4;

// ---- bf16 split helpers (exact two-fold split: x = hi + lo + O(2^-17 x)) ----
__device__ __forceinline__ u16 f2bf(float f) {
    unsigned u = __float_as_uint(f);
    u += 0x7FFF + ((u >> 16) & 1);       // round-to-nearest-even
    return (u16)(u >> 16);
}
__device__ __forceinline__ float bf2f(u16 h) {
    return __uint_as_float((unsigned)h << 16);
}

__device__ __forceinline__ void gload16(const void* g, void* l) {
    __builtin_amdgcn_global_load_lds(
        (const __attribute__((address_space(1))) void*)g,
        (__attribute__((address_space(3))) void*)l, 16, 0, 0);
}

// ---------------------------------------------------------------------------
// Split-bf16 MFMA GEMM.  C[M=4096, N] = A @ B  computed as AhBh + AhBl + AlBh.
// A planes: [M][K] bf16 (hi, lo).  B planes: [N][K] bf16 (already transposed).
// Tile 128 x (NREP*32), BK=32, 4 waves (2x2), each wave 64 x (NREP*16).
// LDS: linear row-major [rows][32] bf16 with slot-XOR swizzle applied on the
// GLOBAL source during global_load_lds staging (m173 pattern) and on ds_read.
// EPI: 0 = fp32 out, 1 = +bias,relu -> hi/lo planes, 2 = +bias -> hi/lo planes
// ---------------------------------------------------------------------------
template<int NREP, int EPI>
__global__ __launch_bounds__(256) void mgemm(
    const u16* __restrict__ Ah, const u16* __restrict__ Al,
    const u16* __restrict__ Bh, const u16* __restrict__ Bl,
    const float* __restrict__ bias,
    float* __restrict__ Cf, u16* __restrict__ Ch, u16* __restrict__ Cl,
    int N, int K)
{
    constexpr int BN = NREP * 32;
    __shared__ u16 sAh[128 * 32];
    __shared__ u16 sAl[128 * 32];
    __shared__ u16 sBh[BN * 32];
    __shared__ u16 sBl[BN * 32];

    const int tid  = threadIdx.x;
    const int wid  = tid >> 6;
    const int lane = tid & 63;
    const int bm = blockIdx.y * 128;
    const int bn = blockIdx.x * BN;

    // staging decode: lane -> (row-in-16, slot); source slot pre-swizzled
    const int lrow  = lane >> 2;                       // 0..15
    const int gslot = (lane & 3) ^ ((lane >> 3) & 3);  // swizzled source slot

    // fragment decode
    const int frow  = lane & 15;
    const int fslot = lane >> 4;                       // 0..3 (k-group)
    const int wm = wid >> 1, wn = wid & 1;

    f32x4 acc[4][NREP];
#pragma unroll
    for (int i = 0; i < 4; ++i)
#pragma unroll
        for (int j = 0; j < NREP; ++j)
#pragma unroll
            for (int r = 0; r < 4; ++r) acc[i][j][r] = 0.f;

    constexpr int NB_ISS = BN / 16;            // issues per B plane
    constexpr int TOT    = 16 + 2 * NB_ISS;    // A:2 planes x 8 + B:2 x NB_ISS
    constexpr int PER_W  = TOT / 4;

    for (int k0 = 0; k0 < K; k0 += 32) {
#pragma unroll
        for (int t = 0; t < PER_W; ++t) {
            int q = wid + 4 * t;               // wave-uniform
            const u16* gp;
            u16* lp;
            if (q < 16) {
                int pl = q >> 3, rb = q & 7;
                const u16* src = pl ? Al : Ah;
                gp = src + (size_t)(bm + rb * 16 + lrow) * K + k0 + gslot * 8;
                lp = (pl ? sAl : sAh) + rb * 512;
            } else {
                int qb = q - 16;
                int pl = qb / NB_ISS, rb = qb % NB_ISS;
                const u16* src = pl ? Bl : Bh;
                gp = src + (size_t)(bn + rb * 16 + lrow) * K + k0 + gslot * 8;
                lp = (pl ? sBl : sBh) + rb * 512;
            }
            gload16(gp, lp);
        }
        __syncthreads();   // compiler emits vmcnt(0) drain before barrier

        short8 bh[NREP], bl[NREP];
#pragma unroll
        for (int j = 0; j < NREP; ++j) {
            int rb = wn * (NREP * 16) + j * 16 + frow;
            int offb = rb * 32 + ((fslot ^ ((rb >> 1) & 3)) * 8);
            bh[j] = *(const short8*)(sBh + offb);
            bl[j] = *(const short8*)(sBl + offb);
        }
#pragma unroll
        for (int i = 0; i < 4; ++i) {
            int ra = wm * 64 + i * 16 + frow;
            int offa = ra * 32 + ((fslot ^ ((ra >> 1) & 3)) * 8);
            short8 ah = *(const short8*)(sAh + offa);
            short8 al = *(const short8*)(sAl + offa);
#pragma unroll
            for (int j = 0; j < NREP; ++j) {
                acc[i][j] = __builtin_amdgcn_mfma_f32_16x16x32_bf16(ah, bh[j], acc[i][j], 0, 0, 0);
                acc[i][j] = __builtin_amdgcn_mfma_f32_16x16x32_bf16(ah, bl[j], acc[i][j], 0, 0, 0);
                acc[i][j] = __builtin_amdgcn_mfma_f32_16x16x32_bf16(al, bh[j], acc[i][j], 0, 0, 0);
            }
        }
        __syncthreads();
    }

    // epilogue: D mapping col = lane&15, row = (lane>>4)*4 + r   [m89-verified]
#pragma unroll
    for (int i = 0; i < 4; ++i) {
#pragma unroll
        for (int j = 0; j < NREP; ++j) {
            int gc = bn + wn * (NREP * 16) + j * 16 + (lane & 15);
            float bv = (EPI >= 1) ? bias[gc] : 0.f;
#pragma unroll
            for (int r = 0; r < 4; ++r) {
                int gr = bm + wm * 64 + i * 16 + (lane >> 4) * 4 + r;
                float vv = acc[i][j][r];
                size_t idx = (size_t)gr * N + gc;
                if (EPI == 0) {
                    Cf[idx] = vv;
                } else {
                    vv += bv;
                    if (EPI == 1) vv = fmaxf(vv, 0.f);
                    u16 h = f2bf(vv);
                    Ch[idx] = h;
                    Cl[idx] = f2bf(vv - bf2f(h));
                }
            }
        }
    }
}

// ---------------------------------------------------------------------------
// Weight transpose + split (+ optional EMA blend): W [K][N] fp32 -> [N][K] planes
// ---------------------------------------------------------------------------
template<int EMA>
__global__ __launch_bounds__(256) void transpose_split(
    const float* __restrict__ Wm, const float* __restrict__ W2,
    const float* __restrict__ mom,
    u16* __restrict__ oh, u16* __restrict__ ol, int K, int N)
{
    __shared__ float t[32][33];
    const int tx = threadIdx.x & 31, ty = threadIdx.x >> 5;   // 32 x 8
    const int bx = blockIdx.x * 32;   // N dir
    const int by = blockIdx.y * 32;   // K dir
    float m = 0.f, m1 = 0.f;
    if (EMA) { m = mom[0]; m1 = 1.f - m; }
#pragma unroll
    for (int r = 0; r < 32; r += 8) {
        size_t gi = (size_t)(by + ty + r) * N + bx + tx;
        float v = Wm[gi];
        if (EMA) v = m * v + m1 * W2[gi];
        t[ty + r][tx] = v;
    }
    __syncthreads();
#pragma unroll
    for (int r = 0; r < 32; r += 8) {
        float v = t[tx][ty + r];
        size_t idx = (size_t)(bx + ty + r) * K + by + tx;
        u16 h = f2bf(v);
        oh[idx] = h;
        ol[idx] = f2bf(v - bf2f(h));
    }
}

// ---------------------------------------------------------------------------
// Elementwise fp32 -> hi/lo planes (for x)
// ---------------------------------------------------------------------------
__global__ void convert_split(const float* __restrict__ X,
                              u16* __restrict__ oh, u16* __restrict__ ol, int total4)
{
    int stride = gridDim.x * blockDim.x;
    for (int t = blockIdx.x * blockDim.x + threadIdx.x; t < total4; t += stride) {
        float4 v = ((const float4*)X)[t];
        ushort4 vh, vl;
        vh.x = f2bf(v.x); vl.x = f2bf(v.x - bf2f(vh.x));
        vh.y = f2bf(v.y); vl.y = f2bf(v.y - bf2f(vh.y));
        vh.z = f2bf(v.z); vl.z = f2bf(v.z - bf2f(vh.z));
        vh.w = f2bf(v.w); vl.w = f2bf(v.w - bf2f(vh.w));
        ((ushort4*)oh)[t] = vh;
        ((ushort4*)ol)[t] = vl;
    }
}

// ---------------------------------------------------------------------------
// BatchNorm stats
// ---------------------------------------------------------------------------
__global__ void bn_stats_partial(const float* __restrict__ X,
                                 float* __restrict__ psum, float* __restrict__ psq,
                                 int C)
{
    int c = blockIdx.x * 256 + threadIdx.x;
    int r0 = blockIdx.y * (NR / 32);
    float s = 0.f, q = 0.f;
    for (int r = r0; r < r0 + (NR / 32); ++r) {
        float v = X[(size_t)r * C + c];
        s += v;
        q = fmaf(v, v, q);
    }
    psum[(size_t)blockIdx.y * C + c] = s;
    psq [(size_t)blockIdx.y * C + c] = q;
}

__global__ void bn_finalize(const float* __restrict__ psum, const float* __restrict__ psq,
                            float* __restrict__ meanb, float* __restrict__ rstdb, int C)
{
    int c = blockIdx.x * 256 + threadIdx.x;
    float s = 0.f, q = 0.f;
    for (int u = 0; u < 32; ++u) {
        s += psum[(size_t)u * C + c];
        q += psq [(size_t)u * C + c];
    }
    float mn  = s * (1.0f / NR);
    float var = q * (1.0f / NR) - mn * mn;
    meanb[c] = mn;
    rstdb[c] = rsqrtf(var + 1e-5f);
}

// BN apply, writing bf16 hi/lo planes.
// MODE 0: (x-m)*rstd ; 1: relu(affine) ; 2: relu(EMA-blended affine)
template<int MODE>
__global__ void bn_apply_p(const float* __restrict__ X,
                           const float* __restrict__ meanb, const float* __restrict__ rstdb,
                           const float* __restrict__ ga, const float* __restrict__ ba,
                           const float* __restrict__ gb, const float* __restrict__ bb,
                           const float* __restrict__ mom,
                           u16* __restrict__ oh, u16* __restrict__ ol,
                           int total4, int C)
{
    float m = 0.f, m1 = 0.f;
    if (MODE == 2) { m = mom[0]; m1 = 1.f - m; }
    int stride = gridDim.x * blockDim.x;
    for (int t = blockIdx.x * blockDim.x + threadIdx.x; t < total4; t += stride) {
        int c = (t << 2) % C;
        float4 v  = ((const float4*)X)[t];
        float4 mn = *(const float4*)(meanb + c);
        float4 rs = *(const float4*)(rstdb + c);
        v.x = (v.x - mn.x) * rs.x; v.y = (v.y - mn.y) * rs.y;
        v.z = (v.z - mn.z) * rs.z; v.w = (v.w - mn.w) * rs.w;
        if (MODE >= 1) {
            float4 gg  = *(const float4*)(ga + c);
            float4 bbv = *(const float4*)(ba + c);
            if (MODE == 2) {
                float4 g2 = *(const float4*)(gb + c);
                float4 b2 = *(const float4*)(bb + c);
                gg.x  = m*gg.x  + m1*g2.x; gg.y  = m*gg.y  + m1*g2.y;
                gg.z  = m*gg.z  + m1*g2.z; gg.w  = m*gg.w  + m1*g2.w;
                bbv.x = m*bbv.x + m1*b2.x; bbv.y = m*bbv.y + m1*b2.y;
                bbv.z = m*bbv.z + m1*b2.z; bbv.w = m*bbv.w + m1*b2.w;
            }
            v.x = fmaxf(fmaf(v.x, gg.x, bbv.x), 0.f);
            v.y = fmaxf(fmaf(v.y, gg.y, bbv.y), 0.f);
            v.z = fmaxf(fmaf(v.z, gg.z, bbv.z), 0.f);
            v.w = fmaxf(fmaf(v.w, gg.w, bbv.w), 0.f);
        }
        ushort4 vh, vl;
        vh.x = f2bf(v.x); vl.x = f2bf(v.x - bf2f(vh.x));
        vh.y = f2bf(v.y); vl.y = f2bf(v.y - bf2f(vh.y));
        vh.z = f2bf(v.z); vl.z = f2bf(v.z - bf2f(vh.z));
        vh.w = f2bf(v.w); vl.w = f2bf(v.w - bf2f(vh.w));
        ((ushort4*)oh)[t] = vh;
        ((ushort4*)ol)[t] = vl;
    }
}

// ---------------------------------------------------------------------------
// Row L2-normalize from planes -> planes. Rows of FF=512, one wave per row.
// ---------------------------------------------------------------------------
__global__ void l2norm_p(const u16* __restrict__ ih, const u16* __restrict__ il,
                         u16* __restrict__ oh, u16* __restrict__ ol)
{
    const int row = blockIdx.x;
    const int lane = threadIdx.x;   // 64
    const short8* ph = (const short8*)(ih + (size_t)row * FF);
    const short8* pl = (const short8*)(il + (size_t)row * FF);
    short8 vh = ph[lane];
    short8 vl = pl[lane];
    float f[8];
    float ss = 0.f;
#pragma unroll
    for (int j = 0; j < 8; ++j) {
        f[j] = bf2f((u16)vh[j]) + bf2f((u16)vl[j]);
        ss = fmaf(f[j], f[j], ss);
    }
#pragma unroll
    for (int o = 32; o > 0; o >>= 1) ss += __shfl_xor(ss, o);
    float sc = 1.f / fmaxf(sqrtf(ss), 1e-12f);
    short8 rh, rl;
#pragma unroll
    for (int j = 0; j < 8; ++j) {
        float y = f[j] * sc;
        u16 h = f2bf(y);
        rh[j] = (short)h;
        rl[j] = (short)f2bf(y - bf2f(h));
    }
    ((short8*)(oh + (size_t)row * FF))[lane] = rh;
    ((short8*)(ol + (size_t)row * FF))[lane] = rl;
}

// ---------------------------------------------------------------------------
// block reductions (256 threads = 4 waves)
// ---------------------------------------------------------------------------
__device__ __forceinline__ float block_sum(float v, float* sred)
{
#pragma unroll
    for (int o = 32; o > 0; o >>= 1) v += __shfl_xor(v, o);
    __syncthreads();
    if ((threadIdx.x & 63) == 0) sred[threadIdx.x >> 6] = v;
    __syncthreads();
    return sred[0] + sred[1] + sred[2] + sred[3];
}
__device__ __forceinline__ float block_max(float v, float* sred)
{
#pragma unroll
    for (int o = 32; o > 0; o >>= 1) v = fmaxf(v, __shfl_xor(v, o));
    __syncthreads();
    if ((threadIdx.x & 63) == 0) sred[threadIdx.x >> 6] = v;
    __syncthreads();
    return fmaxf(fmaxf(sred[0], sred[1]), fmaxf(sred[2], sred[3]));
}

// ---------------------------------------------------------------------------
// kernel_affinity row transform (in place over S = zk_n @ zk_n^T)
// ---------------------------------------------------------------------------
__global__ __launch_bounds__(256) void affinity_rows(float* __restrict__ S,
                                                     float* __restrict__ rowsum)
{
    const int i = blockIdx.x;
    const int tid = threadIdx.x;
    __shared__ float arow[NR];
    __shared__ float sred[4];
    __shared__ float svv[4];
    __shared__ int   sii[4];
    float* Srow = S + (size_t)i * NR;

    float s1 = 0.f;
    for (int j = tid; j < NR; j += 256) {
        float sij = Srow[j];
        float d = fmaxf(2.f - 2.f * sij, 0.f);
        float a = expf(-10.f * d);
        arow[j] = a;
        s1 += a;
    }
    __syncthreads();
    float S1 = block_sum(s1, sred);
    float invS1 = 1.f / S1;
    float Ad = arow[i] * invS1;
    __syncthreads();

    float s2 = 0.f;
    float bv = 3.4e38f; int bi = NR;
    for (int j = tid; j < NR; j += 256) {
        float Aj = arow[j] * invS1;
        arow[j] = Aj;
        float diff = fabsf(Ad - Aj);
        float key = diff + (j == i ? 1.f : 0.f);
        if (key < bv) { bv = key; bi = j; }
        s2 += (j == i) ? 0.f : expf(Aj);
    }
    float S2 = block_sum(s2, sred);

#pragma unroll
    for (int o = 32; o > 0; o >>= 1) {
        float ov = __shfl_xor(bv, o);
        int   oi = __shfl_xor(bi, o);
        if (ov < bv || (ov == bv && oi < bi)) { bv = ov; bi = oi; }
    }
    __syncthreads();
    if ((tid & 63) == 0) { svv[tid >> 6] = bv; sii[tid >> 6] = bi; }
    __syncthreads();
    float fv = svv[0]; int idx = sii[0];
#pragma unroll
    for (int u = 1; u < 4; ++u)
        if (svv[u] < fv || (svv[u] == fv && sii[u] < idx)) { fv = svv[u]; idx = sii[u]; }

    float invS2 = 1.f / S2;
    float s3 = 0.f;
    for (int j = tid; j < NR; j += 256) {
        float Aj = arow[j];
        float diff = fabsf(Ad - Aj);
        float thr = (diff < 0.8f) ? 1.f : 0.f;
        float ind = ((j == idx) ? 1.f : 0.f) + ((j == i) ? 1.f : 0.f);
        float tk = thr * ind;
        float E = (j == i) ? 0.f : expf(Aj);
        float w = 1.f - E * invS2;
        float dyn = tk * w + (1.f - tk);
        float mv2 = Aj * dyn;
        Srow[j] = mv2;
        s3 += mv2;
    }
    float S3 = block_sum(s3, sred);
    if (tid == 0) rowsum[i] = S3;
}

// ---------------------------------------------------------------------------
// contrastive row
// ---------------------------------------------------------------------------
__global__ __launch_bounds__(256) void contrastive_rows(const float* __restrict__ Sim,
                                                        const float* __restrict__ MP,
                                                        const float* __restrict__ mprs,
                                                        double* __restrict__ acc)
{
    const int i = blockIdx.x;
    const int tid = threadIdx.x;
    __shared__ float srow[NR];
    __shared__ float sred[4];
    const float* simr = Sim + (size_t)i * NR;
    const float* mpr  = MP  + (size_t)i * NR;

    float mx = -3.4e38f;
    for (int j = tid; j < NR; j += 256) {
        float s = simr[j] * 2.f;
        srow[j] = s;
        mx = fmaxf(mx, s);
    }
    __syncthreads();
    float M = block_max(mx, sred);
    float se = 0.f;
    for (int j = tid; j < NR; j += 256) se += expf(srow[j] - M);
    float SE = block_sum(se, sred);
    float lse = M + logf(SE);
    float part = 0.f;
    for (int j = tid; j < NR; j += 256) part = fmaf(lse - srow[j], mpr[j], part);
    float P = block_sum(part, sred);
    if (tid == 0) atomicAdd(acc, (double)(P / mprs[i]));
}

__global__ void finalize_k(const double* __restrict__ acc, float* __restrict__ out)
{
    const double nn = (double)NR * (double)NR;
    out[0] = (float)(acc[0] / (3.0 * nn) + acc[1] / (6.0 * nn));
}

// ---------------------------------------------------------------------------
extern "C" void kernel_launch(void* const* d_in, const int* in_sizes, int n_in,
                              void* d_out, int out_size, void* d_ws, size_t ws_size,
                              hipStream_t stream)
{
    const float* x   = (const float*)d_in[0];
    const float* W1  = (const float*)d_in[1];
    const float* g1  = (const float*)d_in[2];
    const float* b1  = (const float*)d_in[3];
    const float* W2  = (const float*)d_in[4];
    const float* g2  = (const float*)d_in[5];
    const float* b2  = (const float*)d_in[6];
    const float* W3  = (const float*)d_in[7];
    const float* tW1 = (const float*)d_in[8];
    const float* tg1 = (const float*)d_in[9];
    const float* tb1 = (const float*)d_in[10];
    const float* tW2 = (const float*)d_in[11];
    const float* tg2 = (const float*)d_in[12];
    const float* tb2 = (const float*)d_in[13];
    const float* tW3 = (const float*)d_in[14];
    const float* dW1 = (const float*)d_in[15];
    const float* db1 = (const float*)d_in[16];
    const float* dW2 = (const float*)d_in[17];
    const float* db2 = (const float*)d_in[18];
    const float* mom = (const float*)d_in[19];
    float* out = (float*)d_out;

    // ---- workspace carve (bytes). sim aliases the first 64MB (xp+wt+hraw,
    // all dead in phase 2). Total ~264 MB. ----
    char* base = (char*)d_ws;
    size_t off = 0;
    auto take = [&](size_t b) { void* p = base + off; off += (b + 255) & ~(size_t)255; return p; };
    u16* xph  = (u16*)take((size_t)NR * DD * 2);
    u16* xpl  = (u16*)take((size_t)NR * DD * 2);
    u16* wth  = (u16*)take((size_t)DD * HH * 2);
    u16* wtl  = (u16*)take((size_t)DD * HH * 2);
    float* hraw = (float*)take((size_t)NR * HH * 4);
    float* sim  = (float*)d_ws;                      // alias (phase 2 only)
    u16* hph  = (u16*)take((size_t)NR * HH * 2);
    u16* hpl  = (u16*)take((size_t)NR * HH * 2);
    u16* zrph = (u16*)take((size_t)NR * FF * 2);
    u16* zrpl = (u16*)take((size_t)NR * FF * 2);
    u16* zqnh = (u16*)take((size_t)VNUM * NR * FF * 2);
    u16* zqnl = (u16*)take((size_t)VNUM * NR * FF * 2);
    u16* zknh = (u16*)take((size_t)VNUM * NR * FF * 2);
    u16* zknl = (u16*)take((size_t)VNUM * NR * FF * 2);
    u16* pnh  = (u16*)take((size_t)VNUM * NR * FF * 2);
    u16* pnl  = (u16*)take((size_t)VNUM * NR * FF * 2);
    float* mp     = (float*)take((size_t)NR * NR * 4);
    float* rowsum = (float*)take((size_t)NR * 4);
    float* psum   = (float*)take((size_t)32 * HH * 4);
    float* psq    = (float*)take((size_t)32 * HH * 4);
    float* meanb  = (float*)take((size_t)HH * 4);
    float* rstdb  = (float*)take((size_t)HH * 4);
    double* acc   = (double*)take(256);

    hipMemsetAsync(acc, 0, 2 * sizeof(double), stream);

    const dim3 TB(256);

    for (int v = 0; v < VNUM; ++v) {
        const float* xv = x + (size_t)v * NR * DD;
        const float* W1v  = W1  + (size_t)v * DD * HH;
        const float* W2v  = W2  + (size_t)v * HH * HH;
        const float* W3v  = W3  + (size_t)v * HH * FF;
        const float* tW1v = tW1 + (size_t)v * DD * HH;
        const float* tW2v = tW2 + (size_t)v * HH * HH;
        const float* tW3v = tW3 + (size_t)v * HH * FF;
        const float* dW1v = dW1 + (size_t)v * FF * HH;
        const float* dW2v = dW2 + (size_t)v * HH * FF;
        const float* g1v = g1 + (size_t)v * HH;   const float* b1v = b1 + (size_t)v * HH;
        const float* g2v = g2 + (size_t)v * HH;   const float* b2v = b2 + (size_t)v * HH;
        const float* tg1v = tg1 + (size_t)v * HH; const float* tb1v = tb1 + (size_t)v * HH;
        const float* tg2v = tg2 + (size_t)v * HH; const float* tb2v = tb2 + (size_t)v * HH;
        const float* db1v = db1 + (size_t)v * HH;
        const float* db2v = db2 + (size_t)v * FF;
        u16* zqnv_h = zqnh + (size_t)v * NR * FF;  u16* zqnv_l = zqnl + (size_t)v * NR * FF;
        u16* zknv_h = zknh + (size_t)v * NR * FF;  u16* zknv_l = zknl + (size_t)v * NR * FF;
        u16* pnv_h  = pnh  + (size_t)v * NR * FF;  u16* pnv_l  = pnl  + (size_t)v * NR * FF;

        convert_split<<<dim3(2048), TB, 0, stream>>>(xv, xph, xpl, NR * DD / 4);

        // ---- online fcn -> zq planes ----
        transpose_split<0><<<dim3(HH/32, DD/32), TB, 0, stream>>>(W1v, nullptr, nullptr, wth, wtl, DD, HH);
        mgemm<4,0><<<dim3(HH/128, NR/128), TB, 0, stream>>>(xph, xpl, wth, wtl, nullptr, hraw, nullptr, nullptr, HH, DD);
        bn_stats_partial<<<dim3(HH/256, 32), TB, 0, stream>>>(hraw, psum, psq, HH);
        bn_finalize<<<dim3(HH/256), TB, 0, stream>>>(psum, psq, meanb, rstdb, HH);
        bn_apply_p<1><<<dim3(2048), TB, 0, stream>>>(hraw, meanb, rstdb, g1v, b1v, nullptr, nullptr, nullptr, hph, hpl, NR*HH/4, HH);

        transpose_split<0><<<dim3(HH/32, HH/32), TB, 0, stream>>>(W2v, nullptr, nullptr, wth, wtl, HH, HH);
        mgemm<4,0><<<dim3(HH/128, NR/128), TB, 0, stream>>>(hph, hpl, wth, wtl, nullptr, hraw, nullptr, nullptr, HH, HH);
        bn_stats_partial<<<dim3(HH/256, 32), TB, 0, stream>>>(hraw, psum, psq, HH);
        bn_finalize<<<dim3(HH/256), TB, 0, stream>>>(psum, psq, meanb, rstdb, HH);
        bn_apply_p<1><<<dim3(2048), TB, 0, stream>>>(hraw, meanb, rstdb, g2v, b2v, nullptr, nullptr, nullptr, hph, hpl, NR*HH/4, HH);

        transpose_split<0><<<dim3(FF/32, HH/32), TB, 0, stream>>>(W3v, nullptr, nullptr, wth, wtl, HH, FF);
        mgemm<2,0><<<dim3(FF/64, NR/128), TB, 0, stream>>>(hph, hpl, wth, wtl, nullptr, hraw, nullptr, nullptr, FF, HH);
        bn_stats_partial<<<dim3(FF/256, 32), TB, 0, stream>>>(hraw, psum, psq, FF);
        bn_finalize<<<dim3(FF/256), TB, 0, stream>>>(psum, psq, meanb, rstdb, FF);
        bn_apply_p<0><<<dim3(2048), TB, 0, stream>>>(hraw, meanb, rstdb, nullptr, nullptr, nullptr, nullptr, nullptr, zrph, zrpl, NR*FF/4, FF);
        l2norm_p<<<dim3(NR), dim3(64), 0, stream>>>(zrph, zrpl, zqnv_h, zqnv_l);

        // ---- mlp on zq raw planes -> p planes ----
        transpose_split<0><<<dim3(HH/32, FF/32), TB, 0, stream>>>(dW1v, nullptr, nullptr, wth, wtl, FF, HH);
        mgemm<4,1><<<dim3(HH/128, NR/128), TB, 0, stream>>>(zrph, zrpl, wth, wtl, db1v, nullptr, hph, hpl, HH, FF);
        transpose_split<0><<<dim3(FF/32, HH/32), TB, 0, stream>>>(dW2v, nullptr, nullptr, wth, wtl, HH, FF);
        mgemm<2,2><<<dim3(FF/64, NR/128), TB, 0, stream>>>(hph, hpl, wth, wtl, db2v, nullptr, zrph, zrpl, FF, HH);
        l2norm_p<<<dim3(NR), dim3(64), 0, stream>>>(zrph, zrpl, pnv_h, pnv_l);

        // ---- target fcn (EMA fused in transpose / bn) -> zk planes ----
        transpose_split<1><<<dim3(HH/32, DD/32), TB, 0, stream>>>(tW1v, W1v, mom, wth, wtl, DD, HH);
        mgemm<4,0><<<dim3(HH/128, NR/128), TB, 0, stream>>>(xph, xpl, wth, wtl, nullptr, hraw, nullptr, nullptr, HH, DD);
        bn_stats_partial<<<dim3(HH/256, 32), TB, 0, stream>>>(hraw, psum, psq, HH);
        bn_finalize<<<dim3(HH/256), TB, 0, stream>>>(psum, psq, meanb, rstdb, HH);
        bn_apply_p<2><<<dim3(2048), TB, 0, stream>>>(hraw, meanb, rstdb, tg1v, tb1v, g1v, b1v, mom, hph, hpl, NR*HH/4, HH);

        transpose_split<1><<<dim3(HH/32, HH/32), TB, 0, stream>>>(tW2v, W2v, mom, wth, wtl, HH, HH);
        mgemm<4,0><<<dim3(HH/128, NR/128), TB, 0, stream>>>(hph, hpl, wth, wtl, nullptr, hraw, nullptr, nullptr, HH, HH);
        bn_stats_partial<<<dim3(HH/256, 32), TB, 0, stream>>>(hraw, psum, psq, HH);
        bn_finalize<<<dim3(HH/256), TB, 0, stream>>>(psum, psq, meanb, rstdb, HH);
        bn_apply_p<2><<<dim3(2048), TB, 0, stream>>>(hraw, meanb, rstdb, tg2v, tb2v, g2v, b2v, mom, hph, hpl, NR*HH/4, HH);

        transpose_split<1><<<dim3(FF/32, HH/32), TB, 0, stream>>>(tW3v, W3v, mom, wth, wtl, HH, FF);
        mgemm<2,0><<<dim3(FF/64, NR/128), TB, 0, stream>>>(hph, hpl, wth, wtl, nullptr, hraw, nullptr, nullptr, FF, HH);
        bn_stats_partial<<<dim3(FF/256, 32), TB, 0, stream>>>(hraw, psum, psq, FF);
        bn_finalize<<<dim3(FF/256), TB, 0, stream>>>(psum, psq, meanb, rstdb, FF);
        bn_apply_p<0><<<dim3(2048), TB, 0, stream>>>(hraw, meanb, rstdb, nullptr, nullptr, nullptr, nullptr, nullptr, zrph, zrpl, NR*FF/4, FF);
        l2norm_p<<<dim3(NR), dim3(64), 0, stream>>>(zrph, zrpl, zknv_h, zknv_l);
    }

    // ---- phase 2: affinity + contrastive (sim aliases xp/wt/hraw region) ----
    const int QA[3] = {1, 0, 0};
    const int QB[3] = {2, 2, 1};
    for (int v = 0; v < VNUM; ++v) {
        u16* zknv_h = zknh + (size_t)v * NR * FF;  u16* zknv_l = zknl + (size_t)v * NR * FF;
        u16* zqnv_h = zqnh + (size_t)v * NR * FF;  u16* zqnv_l = zqnl + (size_t)v * NR * FF;

        mgemm<4,0><<<dim3(NR/128, NR/128), TB, 0, stream>>>(zknv_h, zknv_l, zknv_h, zknv_l, nullptr, mp, nullptr, nullptr, NR, FF);
        affinity_rows<<<dim3(NR), TB, 0, stream>>>(mp, rowsum);

        mgemm<4,0><<<dim3(NR/128, NR/128), TB, 0, stream>>>(zqnv_h, zqnv_l, zknv_h, zknv_l, nullptr, sim, nullptr, nullptr, NR, FF);
        contrastive_rows<<<dim3(NR), TB, 0, stream>>>(sim, mp, rowsum, acc + 0);

        u16* pa_h = pnh + (size_t)QA[v] * NR * FF;  u16* pa_l = pnl + (size_t)QA[v] * NR * FF;
        mgemm<4,0><<<dim3(NR/128, NR/128), TB, 0, stream>>>(pa_h, pa_l, zknv_h, zknv_l, nullptr, sim, nullptr, nullptr, NR, FF);
        contrastive_rows<<<dim3(NR), TB, 0, stream>>>(sim, mp, rowsum, acc + 1);

        u16* pb_h = pnh + (size_t)QB[v] * NR * FF;  u16* pb_l = pnl + (size_t)QB[v] * NR * FF;
        mgemm<4,0><<<dim3(NR/128, NR/128), TB, 0, stream>>>(pb_h, pb_l, zknv_h, zknv_l, nullptr, sim, nullptr, nullptr, NR, FF);
        contrastive_rows<<<dim3(NR), TB, 0, stream>>>(sim, mp, rowsum, acc + 1);
    }

    finalize_k<<<dim3(1), dim3(1), 0, stream>>>(acc, out);
}

// Round 4
// 3619.591 us; speedup vs baseline: 3.1500x; 1.2116x over previous
//
#include <hip/hip_runtime.h>

#define NR 4096
#define DD 2048
#define HH 2048
#define FF 512
#define VNUM 3

typedef unsigned short u16;
typedef __attribute__((ext_vector_type(8))) short short8;
typedef __attribute__((ext_vector_type(4))) float f32x4;

// ---- bf16 helpers ----
__device__ __forceinline__ u16 f2bf(float f) {
    unsigned u = __float_as_uint(f);
    u += 0x7FFF + ((u >> 16) & 1);       // round-to-nearest-even
    return (u16)(u >> 16);
}
__device__ __forceinline__ float bf2f(u16 h) {
    return __uint_as_float((unsigned)h << 16);
}

__device__ __forceinline__ void gload16(const void* g, void* l) {
    __builtin_amdgcn_global_load_lds(
        (const __attribute__((address_space(1))) void*)g,
        (__attribute__((address_space(3))) void*)l, 16, 0, 0);
}

// ---------------------------------------------------------------------------
// Split-bf16 MFMA GEMM, 2-term: C = (Ah + Al) @ Bh   (B bf16-rounded).
// A planes: [M][K] bf16 hi+lo.  B plane: [N][K] bf16 hi only.
// Tile 128 x (NREP*32), BK=32, 4 waves (2x2).
// STATS=1: accumulate column sum/sumsq of C into psum/psq (pre-zeroed;
//          bn_finalize re-zeroes after consuming).
// EPI: 0 = fp32 out, 1 = +bias,relu -> planes, 2 = +bias -> planes
// ---------------------------------------------------------------------------
template<int NREP, int EPI, int STATS>
__global__ __launch_bounds__(256) void mgemm(
    const u16* __restrict__ Ah, const u16* __restrict__ Al,
    const u16* __restrict__ Bh,
    const float* __restrict__ bias,
    float* __restrict__ Cf, u16* __restrict__ Ch, u16* __restrict__ Cl,
    float* __restrict__ psum, float* __restrict__ psq,
    int N, int K)
{
    constexpr int BN = NREP * 32;
    __shared__ u16 sAh[128 * 32];
    __shared__ u16 sAl[128 * 32];
    __shared__ u16 sBh[BN * 32];

    const int tid  = threadIdx.x;
    const int wid  = tid >> 6;
    const int lane = tid & 63;
    const int bm = blockIdx.y * 128;
    const int bn = blockIdx.x * BN;

    // staging decode: lane -> (row-in-16, slot); source slot pre-swizzled
    const int lrow  = lane >> 2;                       // 0..15
    const int gslot = (lane & 3) ^ ((lane >> 3) & 3);  // swizzled source slot

    // fragment decode
    const int frow  = lane & 15;
    const int fslot = lane >> 4;                       // 0..3 (k-group)
    const int wm = wid >> 1, wn = wid & 1;

    f32x4 acc[4][NREP];
#pragma unroll
    for (int i = 0; i < 4; ++i)
#pragma unroll
        for (int j = 0; j < NREP; ++j)
#pragma unroll
            for (int r = 0; r < 4; ++r) acc[i][j][r] = 0.f;

    constexpr int NB_ISS = BN / 16;            // issues for B hi plane
    constexpr int TOT    = 16 + NB_ISS;        // A: 2 planes x 8, B: NB_ISS
    constexpr int PER_W  = TOT / 4;

    for (int k0 = 0; k0 < K; k0 += 32) {
#pragma unroll
        for (int t = 0; t < PER_W; ++t) {
            int q = wid + 4 * t;               // wave-uniform
            const u16* gp;
            u16* lp;
            if (q < 16) {
                int pl = q >> 3, rb = q & 7;
                const u16* src = pl ? Al : Ah;
                gp = src + (size_t)(bm + rb * 16 + lrow) * K + k0 + gslot * 8;
                lp = (pl ? sAl : sAh) + rb * 512;
            } else {
                int rb = q - 16;
                gp = Bh + (size_t)(bn + rb * 16 + lrow) * K + k0 + gslot * 8;
                lp = sBh + rb * 512;
            }
            gload16(gp, lp);
        }
        __syncthreads();

        short8 bh[NREP];
#pragma unroll
        for (int j = 0; j < NREP; ++j) {
            int rb = wn * (NREP * 16) + j * 16 + frow;
            int offb = rb * 32 + ((fslot ^ ((rb >> 1) & 3)) * 8);
            bh[j] = *(const short8*)(sBh + offb);
        }
#pragma unroll
        for (int i = 0; i < 4; ++i) {
            int ra = wm * 64 + i * 16 + frow;
            int offa = ra * 32 + ((fslot ^ ((ra >> 1) & 3)) * 8);
            short8 ah = *(const short8*)(sAh + offa);
            short8 al = *(const short8*)(sAl + offa);
#pragma unroll
            for (int j = 0; j < NREP; ++j) {
                acc[i][j] = __builtin_amdgcn_mfma_f32_16x16x32_bf16(ah, bh[j], acc[i][j], 0, 0, 0);
                acc[i][j] = __builtin_amdgcn_mfma_f32_16x16x32_bf16(al, bh[j], acc[i][j], 0, 0, 0);
            }
        }
        __syncthreads();
    }

    // per-thread partial column stats (fixed column per j across i,r)
    float sj[NREP], qj[NREP];
#pragma unroll
    for (int j = 0; j < NREP; ++j) { sj[j] = 0.f; qj[j] = 0.f; }

    // epilogue: D mapping col = lane&15, row = (lane>>4)*4 + r   [m89-verified]
#pragma unroll
    for (int i = 0; i < 4; ++i) {
#pragma unroll
        for (int j = 0; j < NREP; ++j) {
            int gc = bn + wn * (NREP * 16) + j * 16 + (lane & 15);
            float bv = (EPI >= 1) ? bias[gc] : 0.f;
#pragma unroll
            for (int r = 0; r < 4; ++r) {
                int gr = bm + wm * 64 + i * 16 + (lane >> 4) * 4 + r;
                float vv = acc[i][j][r];
                size_t idx = (size_t)gr * N + gc;
                if (EPI == 0) {
                    Cf[idx] = vv;
                    if (STATS) { sj[j] += vv; qj[j] = fmaf(vv, vv, qj[j]); }
                } else {
                    vv += bv;
                    if (EPI == 1) vv = fmaxf(vv, 0.f);
                    u16 h = f2bf(vv);
                    Ch[idx] = h;
                    Cl[idx] = f2bf(vv - bf2f(h));
                }
            }
        }
    }

    if constexpr (STATS) {
        __shared__ float sstat[2 * BN];
        for (int t = tid; t < 2 * BN; t += 256) sstat[t] = 0.f;
        __syncthreads();
#pragma unroll
        for (int j = 0; j < NREP; ++j) {
            float s = sj[j], q = qj[j];
            s += __shfl_xor(s, 16); q += __shfl_xor(q, 16);
            s += __shfl_xor(s, 32); q += __shfl_xor(q, 32);
            if ((lane >> 4) == 0) {
                int cl = wn * (NREP * 16) + j * 16 + (lane & 15);
                atomicAdd(&sstat[cl], s);
                atomicAdd(&sstat[BN + cl], q);
            }
        }
        __syncthreads();
        for (int t = tid; t < BN; t += 256) {
            atomicAdd(psum + bn + t, sstat[t]);
            atomicAdd(psq  + bn + t, sstat[BN + t]);
        }
    }
}

// ---------------------------------------------------------------------------
// Weight transpose + bf16 round (+ optional EMA blend): [K][N] fp32 -> [N][K] hi
// ---------------------------------------------------------------------------
template<int EMA>
__global__ __launch_bounds__(256) void transpose_split(
    const float* __restrict__ Wm, const float* __restrict__ W2,
    const float* __restrict__ mom,
    u16* __restrict__ oh, int K, int N)
{
    __shared__ float t[32][33];
    const int tx = threadIdx.x & 31, ty = threadIdx.x >> 5;   // 32 x 8
    const int bx = blockIdx.x * 32;   // N dir
    const int by = blockIdx.y * 32;   // K dir
    float m = 0.f, m1 = 0.f;
    if (EMA) { m = mom[0]; m1 = 1.f - m; }
#pragma unroll
    for (int r = 0; r < 32; r += 8) {
        size_t gi = (size_t)(by + ty + r) * N + bx + tx;
        float v = Wm[gi];
        if (EMA) v = m * v + m1 * W2[gi];
        t[ty + r][tx] = v;
    }
    __syncthreads();
#pragma unroll
    for (int r = 0; r < 32; r += 8) {
        float v = t[tx][ty + r];
        oh[(size_t)(bx + ty + r) * K + by + tx] = f2bf(v);
    }
}

// ---------------------------------------------------------------------------
// Elementwise fp32 -> hi/lo planes (for x, which is the full-precision A side)
// ---------------------------------------------------------------------------
__global__ void convert_split(const float* __restrict__ X,
                              u16* __restrict__ oh, u16* __restrict__ ol, int total4)
{
    int stride = gridDim.x * blockDim.x;
    for (int t = blockIdx.x * blockDim.x + threadIdx.x; t < total4; t += stride) {
        float4 v = ((const float4*)X)[t];
        ushort4 vh, vl;
        vh.x = f2bf(v.x); vl.x = f2bf(v.x - bf2f(vh.x));
        vh.y = f2bf(v.y); vl.y = f2bf(v.y - bf2f(vh.y));
        vh.z = f2bf(v.z); vl.z = f2bf(v.z - bf2f(vh.z));
        vh.w = f2bf(v.w); vl.w = f2bf(v.w - bf2f(vh.w));
        ((ushort4*)oh)[t] = vh;
        ((ushort4*)ol)[t] = vl;
    }
}

// ---------------------------------------------------------------------------
// BN finalize: consume accumulated psum/psq, re-zero them for the next GEMM.
// ---------------------------------------------------------------------------
__global__ void bn_finalize(float* __restrict__ psum, float* __restrict__ psq,
                            float* __restrict__ meanb, float* __restrict__ rstdb)
{
    int c = blockIdx.x * 256 + threadIdx.x;
    float s = psum[c], q = psq[c];
    psum[c] = 0.f; psq[c] = 0.f;
    float mn  = s * (1.0f / NR);
    float var = q * (1.0f / NR) - mn * mn;
    meanb[c] = mn;
    rstdb[c] = rsqrtf(var + 1e-5f);
}

// BN apply for H-wide layers, writing bf16 hi/lo planes.
// MODE 1: relu(affine) ; MODE 2: relu(EMA-blended affine)
template<int MODE>
__global__ void bn_apply_p(const float* __restrict__ X,
                           const float* __restrict__ meanb, const float* __restrict__ rstdb,
                           const float* __restrict__ ga, const float* __restrict__ ba,
                           const float* __restrict__ gb, const float* __restrict__ bb,
                           const float* __restrict__ mom,
                           u16* __restrict__ oh, u16* __restrict__ ol,
                           int total4, int C)
{
    float m = 0.f, m1 = 0.f;
    if (MODE == 2) { m = mom[0]; m1 = 1.f - m; }
    int stride = gridDim.x * blockDim.x;
    for (int t = blockIdx.x * blockDim.x + threadIdx.x; t < total4; t += stride) {
        int c = (t << 2) % C;
        float4 v  = ((const float4*)X)[t];
        float4 mn = *(const float4*)(meanb + c);
        float4 rs = *(const float4*)(rstdb + c);
        v.x = (v.x - mn.x) * rs.x; v.y = (v.y - mn.y) * rs.y;
        v.z = (v.z - mn.z) * rs.z; v.w = (v.w - mn.w) * rs.w;
        float4 gg  = *(const float4*)(ga + c);
        float4 bbv = *(const float4*)(ba + c);
        if (MODE == 2) {
            float4 g2 = *(const float4*)(gb + c);
            float4 b2 = *(const float4*)(bb + c);
            gg.x  = m*gg.x  + m1*g2.x; gg.y  = m*gg.y  + m1*g2.y;
            gg.z  = m*gg.z  + m1*g2.z; gg.w  = m*gg.w  + m1*g2.w;
            bbv.x = m*bbv.x + m1*b2.x; bbv.y = m*bbv.y + m1*b2.y;
            bbv.z = m*bbv.z + m1*b2.z; bbv.w = m*bbv.w + m1*b2.w;
        }
        v.x = fmaxf(fmaf(v.x, gg.x, bbv.x), 0.f);
        v.y = fmaxf(fmaf(v.y, gg.y, bbv.y), 0.f);
        v.z = fmaxf(fmaf(v.z, gg.z, bbv.z), 0.f);
        v.w = fmaxf(fmaf(v.w, gg.w, bbv.w), 0.f);
        ushort4 vh, vl;
        vh.x = f2bf(v.x); vl.x = f2bf(v.x - bf2f(vh.x));
        vh.y = f2bf(v.y); vl.y = f2bf(v.y - bf2f(vh.y));
        vh.z = f2bf(v.z); vl.z = f2bf(v.z - bf2f(vh.z));
        vh.w = f2bf(v.w); vl.w = f2bf(v.w - bf2f(vh.w));
        ((ushort4*)oh)[t] = vh;
        ((ushort4*)ol)[t] = vl;
    }
}

// ---------------------------------------------------------------------------
// Fused BN(no-affine) + row L2-normalize for F=512-wide outputs.
// One wave per row. WRITE_RAW=1 additionally writes the pre-norm planes.
// ---------------------------------------------------------------------------
template<int WRITE_RAW>
__global__ void bn_l2_rows(const float* __restrict__ X,
                           const float* __restrict__ meanb, const float* __restrict__ rstdb,
                           u16* __restrict__ rh, u16* __restrict__ rl,
                           u16* __restrict__ onh, u16* __restrict__ onl)
{
    const int row = blockIdx.x;
    const int lane = threadIdx.x;   // 64
    const int c0 = lane * 8;
    const float4* xr  = (const float4*)(X + (size_t)row * FF + c0);
    const float4* mnp = (const float4*)(meanb + c0);
    const float4* rsp = (const float4*)(rstdb + c0);
    float4 v0 = xr[0], v1 = xr[1];
    float4 m0 = mnp[0], m1 = mnp[1];
    float4 r0 = rsp[0], r1 = rsp[1];
    float f[8];
    f[0] = (v0.x - m0.x) * r0.x; f[1] = (v0.y - m0.y) * r0.y;
    f[2] = (v0.z - m0.z) * r0.z; f[3] = (v0.w - m0.w) * r0.w;
    f[4] = (v1.x - m1.x) * r1.x; f[5] = (v1.y - m1.y) * r1.y;
    f[6] = (v1.z - m1.z) * r1.z; f[7] = (v1.w - m1.w) * r1.w;
    if (WRITE_RAW) {
        ushort4 h0, l0, h1, l1;
        h0.x = f2bf(f[0]); l0.x = f2bf(f[0] - bf2f(h0.x));
        h0.y = f2bf(f[1]); l0.y = f2bf(f[1] - bf2f(h0.y));
        h0.z = f2bf(f[2]); l0.z = f2bf(f[2] - bf2f(h0.z));
        h0.w = f2bf(f[3]); l0.w = f2bf(f[3] - bf2f(h0.w));
        h1.x = f2bf(f[4]); l1.x = f2bf(f[4] - bf2f(h1.x));
        h1.y = f2bf(f[5]); l1.y = f2bf(f[5] - bf2f(h1.y));
        h1.z = f2bf(f[6]); l1.z = f2bf(f[6] - bf2f(h1.z));
        h1.w = f2bf(f[7]); l1.w = f2bf(f[7] - bf2f(h1.w));
        ushort4* ph = (ushort4*)(rh + (size_t)row * FF + c0);
        ushort4* pl = (ushort4*)(rl + (size_t)row * FF + c0);
        ph[0] = h0; ph[1] = h1;
        pl[0] = l0; pl[1] = l1;
    }
    float ss = 0.f;
#pragma unroll
    for (int j = 0; j < 8; ++j) ss = fmaf(f[j], f[j], ss);
#pragma unroll
    for (int o = 32; o > 0; o >>= 1) ss += __shfl_xor(ss, o);
    float sc = 1.f / fmaxf(sqrtf(ss), 1e-12f);
    ushort4 nh0, nl0, nh1, nl1;
    float y;
    y = f[0] * sc; nh0.x = f2bf(y); nl0.x = f2bf(y - bf2f(nh0.x));
    y = f[1] * sc; nh0.y = f2bf(y); nl0.y = f2bf(y - bf2f(nh0.y));
    y = f[2] * sc; nh0.z = f2bf(y); nl0.z = f2bf(y - bf2f(nh0.z));
    y = f[3] * sc; nh0.w = f2bf(y); nl0.w = f2bf(y - bf2f(nh0.w));
    y = f[4] * sc; nh1.x = f2bf(y); nl1.x = f2bf(y - bf2f(nh1.x));
    y = f[5] * sc; nh1.y = f2bf(y); nl1.y = f2bf(y - bf2f(nh1.y));
    y = f[6] * sc; nh1.z = f2bf(y); nl1.z = f2bf(y - bf2f(nh1.z));
    y = f[7] * sc; nh1.w = f2bf(y); nl1.w = f2bf(y - bf2f(nh1.w));
    ushort4* qh = (ushort4*)(onh + (size_t)row * FF + c0);
    ushort4* ql = (ushort4*)(onl + (size_t)row * FF + c0);
    qh[0] = nh0; qh[1] = nh1;
    ql[0] = nl0; ql[1] = nl1;
}

// ---------------------------------------------------------------------------
// Row L2-normalize planes -> planes (p path). One wave per row.
// ---------------------------------------------------------------------------
__global__ void l2norm_p(const u16* __restrict__ ih, const u16* __restrict__ il,
                         u16* __restrict__ oh, u16* __restrict__ ol)
{
    const int row = blockIdx.x;
    const int lane = threadIdx.x;   // 64
    const short8* ph = (const short8*)(ih + (size_t)row * FF);
    const short8* pl = (const short8*)(il + (size_t)row * FF);
    short8 vh = ph[lane];
    short8 vl = pl[lane];
    float f[8];
    float ss = 0.f;
#pragma unroll
    for (int j = 0; j < 8; ++j) {
        f[j] = bf2f((u16)vh[j]) + bf2f((u16)vl[j]);
        ss = fmaf(f[j], f[j], ss);
    }
#pragma unroll
    for (int o = 32; o > 0; o >>= 1) ss += __shfl_xor(ss, o);
    float sc = 1.f / fmaxf(sqrtf(ss), 1e-12f);
    short8 rh, rl;
#pragma unroll
    for (int j = 0; j < 8; ++j) {
        float y = f[j] * sc;
        u16 h = f2bf(y);
        rh[j] = (short)h;
        rl[j] = (short)f2bf(y - bf2f(h));
    }
    ((short8*)(oh + (size_t)row * FF))[lane] = rh;
    ((short8*)(ol + (size_t)row * FF))[lane] = rl;
}

// ---------------------------------------------------------------------------
// block reductions (256 threads = 4 waves)
// ---------------------------------------------------------------------------
__device__ __forceinline__ float block_sum(float v, float* sred)
{
#pragma unroll
    for (int o = 32; o > 0; o >>= 1) v += __shfl_xor(v, o);
    __syncthreads();
    if ((threadIdx.x & 63) == 0) sred[threadIdx.x >> 6] = v;
    __syncthreads();
    return sred[0] + sred[1] + sred[2] + sred[3];
}
__device__ __forceinline__ float block_max(float v, float* sred)
{
#pragma unroll
    for (int o = 32; o > 0; o >>= 1) v = fmaxf(v, __shfl_xor(v, o));
    __syncthreads();
    if ((threadIdx.x & 63) == 0) sred[threadIdx.x >> 6] = v;
    __syncthreads();
    return fmaxf(fmaxf(sred[0], sred[1]), fmaxf(sred[2], sred[3]));
}

// ---------------------------------------------------------------------------
// kernel_affinity row transform (in place over S = zk_n @ zk_n^T)
// ---------------------------------------------------------------------------
__global__ __launch_bounds__(256) void affinity_rows(float* __restrict__ S,
                                                     float* __restrict__ rowsum)
{
    const int i = blockIdx.x;
    const int tid = threadIdx.x;
    __shared__ float arow[NR];
    __shared__ float sred[4];
    __shared__ float svv[4];
    __shared__ int   sii[4];
    float* Srow = S + (size_t)i * NR;

    float s1 = 0.f;
    for (int j = tid; j < NR; j += 256) {
        float sij = Srow[j];
        float d = fmaxf(2.f - 2.f * sij, 0.f);
        float a = expf(-10.f * d);
        arow[j] = a;
        s1 += a;
    }
    __syncthreads();
    float S1 = block_sum(s1, sred);
    float invS1 = 1.f / S1;
    float Ad = arow[i] * invS1;
    __syncthreads();

    float s2 = 0.f;
    float bv = 3.4e38f; int bi = NR;
    for (int j = tid; j < NR; j += 256) {
        float Aj = arow[j] * invS1;
        arow[j] = Aj;
        float diff = fabsf(Ad - Aj);
        float key = diff + (j == i ? 1.f : 0.f);
        if (key < bv) { bv = key; bi = j; }
        s2 += (j == i) ? 0.f : expf(Aj);
    }
    float S2 = block_sum(s2, sred);

#pragma unroll
    for (int o = 32; o > 0; o >>= 1) {
        float ov = __shfl_xor(bv, o);
        int   oi = __shfl_xor(bi, o);
        if (ov < bv || (ov == bv && oi < bi)) { bv = ov; bi = oi; }
    }
    __syncthreads();
    if ((tid & 63) == 0) { svv[tid >> 6] = bv; sii[tid >> 6] = bi; }
    __syncthreads();
    float fv = svv[0]; int idx = sii[0];
#pragma unroll
    for (int u = 1; u < 4; ++u)
        if (svv[u] < fv || (svv[u] == fv && sii[u] < idx)) { fv = svv[u]; idx = sii[u]; }

    float invS2 = 1.f / S2;
    float s3 = 0.f;
    for (int j = tid; j < NR; j += 256) {
        float Aj = arow[j];
        float diff = fabsf(Ad - Aj);
        float thr = (diff < 0.8f) ? 1.f : 0.f;
        float ind = ((j == idx) ? 1.f : 0.f) + ((j == i) ? 1.f : 0.f);
        float tk = thr * ind;
        float E = (j == i) ? 0.f : expf(Aj);
        float w = 1.f - E * invS2;
        float dyn = tk * w + (1.f - tk);
        float mv2 = Aj * dyn;
        Srow[j] = mv2;
        s3 += mv2;
    }
    float S3 = block_sum(s3, sred);
    if (tid == 0) rowsum[i] = S3;
}

// ---------------------------------------------------------------------------
// contrastive row
// ---------------------------------------------------------------------------
__global__ __launch_bounds__(256) void contrastive_rows(const float* __restrict__ Sim,
                                                        const float* __restrict__ MP,
                                                        const float* __restrict__ mprs,
                                                        double* __restrict__ acc)
{
    const int i = blockIdx.x;
    const int tid = threadIdx.x;
    __shared__ float srow[NR];
    __shared__ float sred[4];
    const float* simr = Sim + (size_t)i * NR;
    const float* mpr  = MP  + (size_t)i * NR;

    float mx = -3.4e38f;
    for (int j = tid; j < NR; j += 256) {
        float s = simr[j] * 2.f;
        srow[j] = s;
        mx = fmaxf(mx, s);
    }
    __syncthreads();
    float M = block_max(mx, sred);
    float se = 0.f;
    for (int j = tid; j < NR; j += 256) se += expf(srow[j] - M);
    float SE = block_sum(se, sred);
    float lse = M + logf(SE);
    float part = 0.f;
    for (int j = tid; j < NR; j += 256) part = fmaf(lse - srow[j], mpr[j], part);
    float P = block_sum(part, sred);
    if (tid == 0) atomicAdd(acc, (double)(P / mprs[i]));
}

__global__ void finalize_k(const double* __restrict__ acc, float* __restrict__ out)
{
    const double nn = (double)NR * (double)NR;
    out[0] = (float)(acc[0] / (3.0 * nn) + acc[1] / (6.0 * nn));
}

// ---------------------------------------------------------------------------
extern "C" void kernel_launch(void* const* d_in, const int* in_sizes, int n_in,
                              void* d_out, int out_size, void* d_ws, size_t ws_size,
                              hipStream_t stream)
{
    const float* x   = (const float*)d_in[0];
    const float* W1  = (const float*)d_in[1];
    const float* g1  = (const float*)d_in[2];
    const float* b1  = (const float*)d_in[3];
    const float* W2  = (const float*)d_in[4];
    const float* g2  = (const float*)d_in[5];
    const float* b2  = (const float*)d_in[6];
    const float* W3  = (const float*)d_in[7];
    const float* tW1 = (const float*)d_in[8];
    const float* tg1 = (const float*)d_in[9];
    const float* tb1 = (const float*)d_in[10];
    const float* tW2 = (const float*)d_in[11];
    const float* tg2 = (const float*)d_in[12];
    const float* tb2 = (const float*)d_in[13];
    const float* tW3 = (const float*)d_in[14];
    const float* dW1 = (const float*)d_in[15];
    const float* db1 = (const float*)d_in[16];
    const float* dW2 = (const float*)d_in[17];
    const float* db2 = (const float*)d_in[18];
    const float* mom = (const float*)d_in[19];
    float* out = (float*)d_out;

    // ---- workspace carve. sim (64MB) aliases xp/wt/hraw (72MB, dead in ph2).
    char* base = (char*)d_ws;
    size_t off = 0;
    auto take = [&](size_t b) { void* p = base + off; off += (b + 255) & ~(size_t)255; return p; };
    u16* xph  = (u16*)take((size_t)NR * DD * 2);      // 16MB
    u16* xpl  = (u16*)take((size_t)NR * DD * 2);      // 16MB
    u16* wth  = (u16*)take((size_t)DD * HH * 2);      // 8MB
    float* hraw = (float*)take((size_t)NR * HH * 4);  // 32MB
    float* sim  = (float*)d_ws;                       // alias (phase 2 only)
    u16* hph  = (u16*)take((size_t)NR * HH * 2);
    u16* hpl  = (u16*)take((size_t)NR * HH * 2);
    u16* zrph = (u16*)take((size_t)NR * FF * 2);
    u16* zrpl = (u16*)take((size_t)NR * FF * 2);
    u16* zqnh = (u16*)take((size_t)VNUM * NR * FF * 2);
    u16* zqnl = (u16*)take((size_t)VNUM * NR * FF * 2);
    u16* zknh = (u16*)take((size_t)VNUM * NR * FF * 2);
    u16* zknl = (u16*)take((size_t)VNUM * NR * FF * 2);
    u16* pnh  = (u16*)take((size_t)VNUM * NR * FF * 2);
    u16* pnl  = (u16*)take((size_t)VNUM * NR * FF * 2);
    float* mp     = (float*)take((size_t)NR * NR * 4);
    float* rowsum = (float*)take((size_t)NR * 4);
    float* psum   = (float*)take((size_t)HH * 4);     // adjacent to psq
    float* psq    = (float*)take((size_t)HH * 4);
    float* meanb  = (float*)take((size_t)HH * 4);
    float* rstdb  = (float*)take((size_t)HH * 4);
    double* acc   = (double*)take(256);

    hipMemsetAsync(acc, 0, 2 * sizeof(double), stream);
    hipMemsetAsync(psum, 0, (size_t)2 * HH * 4, stream);   // covers psum+psq

    const dim3 TB(256);

    for (int v = 0; v < VNUM; ++v) {
        const float* xv = x + (size_t)v * NR * DD;
        const float* W1v  = W1  + (size_t)v * DD * HH;
        const float* W2v  = W2  + (size_t)v * HH * HH;
        const float* W3v  = W3  + (size_t)v * HH * FF;
        const float* tW1v = tW1 + (size_t)v * DD * HH;
        const float* tW2v = tW2 + (size_t)v * HH * HH;
        const float* tW3v = tW3 + (size_t)v * HH * FF;
        const float* dW1v = dW1 + (size_t)v * FF * HH;
        const float* dW2v = dW2 + (size_t)v * HH * FF;
        const float* g1v = g1 + (size_t)v * HH;   const float* b1v = b1 + (size_t)v * HH;
        const float* g2v = g2 + (size_t)v * HH;   const float* b2v = b2 + (size_t)v * HH;
        const float* tg1v = tg1 + (size_t)v * HH; const float* tb1v = tb1 + (size_t)v * HH;
        const float* tg2v = tg2 + (size_t)v * HH; const float* tb2v = tb2 + (size_t)v * HH;
        const float* db1v = db1 + (size_t)v * HH;
        const float* db2v = db2 + (size_t)v * FF;
        u16* zqnv_h = zqnh + (size_t)v * NR * FF;  u16* zqnv_l = zqnl + (size_t)v * NR * FF;
        u16* zknv_h = zknh + (size_t)v * NR * FF;  u16* zknv_l = zknl + (size_t)v * NR * FF;
        u16* pnv_h  = pnh  + (size_t)v * NR * FF;  u16* pnv_l  = pnl  + (size_t)v * NR * FF;

        convert_split<<<dim3(2048), TB, 0, stream>>>(xv, xph, xpl, NR * DD / 4);

        // ---- online fcn -> zq ----
        transpose_split<0><<<dim3(HH/32, DD/32), TB, 0, stream>>>(W1v, nullptr, nullptr, wth, DD, HH);
        mgemm<4,0,1><<<dim3(HH/128, NR/128), TB, 0, stream>>>(xph, xpl, wth, nullptr, hraw, nullptr, nullptr, psum, psq, HH, DD);
        bn_finalize<<<dim3(HH/256), TB, 0, stream>>>(psum, psq, meanb, rstdb);
        bn_apply_p<1><<<dim3(2048), TB, 0, stream>>>(hraw, meanb, rstdb, g1v, b1v, nullptr, nullptr, nullptr, hph, hpl, NR*HH/4, HH);

        transpose_split<0><<<dim3(HH/32, HH/32), TB, 0, stream>>>(W2v, nullptr, nullptr, wth, HH, HH);
        mgemm<4,0,1><<<dim3(HH/128, NR/128), TB, 0, stream>>>(hph, hpl, wth, nullptr, hraw, nullptr, nullptr, psum, psq, HH, HH);
        bn_finalize<<<dim3(HH/256), TB, 0, stream>>>(psum, psq, meanb, rstdb);
        bn_apply_p<1><<<dim3(2048), TB, 0, stream>>>(hraw, meanb, rstdb, g2v, b2v, nullptr, nullptr, nullptr, hph, hpl, NR*HH/4, HH);

        transpose_split<0><<<dim3(FF/32, HH/32), TB, 0, stream>>>(W3v, nullptr, nullptr, wth, HH, FF);
        mgemm<2,0,1><<<dim3(FF/64, NR/128), TB, 0, stream>>>(hph, hpl, wth, nullptr, hraw, nullptr, nullptr, psum, psq, FF, HH);
        bn_finalize<<<dim3(FF/256), TB, 0, stream>>>(psum, psq, meanb, rstdb);
        bn_l2_rows<1><<<dim3(NR), dim3(64), 0, stream>>>(hraw, meanb, rstdb, zrph, zrpl, zqnv_h, zqnv_l);

        // ---- mlp on raw zq planes -> p ----
        transpose_split<0><<<dim3(HH/32, FF/32), TB, 0, stream>>>(dW1v, nullptr, nullptr, wth, FF, HH);
        mgemm<4,1,0><<<dim3(HH/128, NR/128), TB, 0, stream>>>(zrph, zrpl, wth, db1v, nullptr, hph, hpl, nullptr, nullptr, HH, FF);
        transpose_split<0><<<dim3(FF/32, HH/32), TB, 0, stream>>>(dW2v, nullptr, nullptr, wth, HH, FF);
        mgemm<2,2,0><<<dim3(FF/64, NR/128), TB, 0, stream>>>(hph, hpl, wth, db2v, nullptr, zrph, zrpl, nullptr, nullptr, FF, HH);
        l2norm_p<<<dim3(NR), dim3(64), 0, stream>>>(zrph, zrpl, pnv_h, pnv_l);

        // ---- target fcn (EMA fused in transpose / bn) -> zk ----
        transpose_split<1><<<dim3(HH/32, DD/32), TB, 0, stream>>>(tW1v, W1v, mom, wth, DD, HH);
        mgemm<4,0,1><<<dim3(HH/128, NR/128), TB, 0, stream>>>(xph, xpl, wth, nullptr, hraw, nullptr, nullptr, psum, psq, HH, DD);
        bn_finalize<<<dim3(HH/256), TB, 0, stream>>>(psum, psq, meanb, rstdb);
        bn_apply_p<2><<<dim3(2048), TB, 0, stream>>>(hraw, meanb, rstdb, tg1v, tb1v, g1v, b1v, mom, hph, hpl, NR*HH/4, HH);

        transpose_split<1><<<dim3(HH/32, HH/32), TB, 0, stream>>>(tW2v, W2v, mom, wth, HH, HH);
        mgemm<4,0,1><<<dim3(HH/128, NR/128), TB, 0, stream>>>(hph, hpl, wth, nullptr, hraw, nullptr, nullptr, psum, psq, HH, HH);
        bn_finalize<<<dim3(HH/256), TB, 0, stream>>>(psum, psq, meanb, rstdb);
        bn_apply_p<2><<<dim3(2048), TB, 0, stream>>>(hraw, meanb, rstdb, tg2v, tb2v, g2v, b2v, mom, hph, hpl, NR*HH/4, HH);

        transpose_split<1><<<dim3(FF/32, HH/32), TB, 0, stream>>>(tW3v, W3v, mom, wth, HH, FF);
        mgemm<2,0,1><<<dim3(FF/64, NR/128), TB, 0, stream>>>(hph, hpl, wth, nullptr, hraw, nullptr, nullptr, psum, psq, FF, HH);
        bn_finalize<<<dim3(FF/256), TB, 0, stream>>>(psum, psq, meanb, rstdb);
        bn_l2_rows<0><<<dim3(NR), dim3(64), 0, stream>>>(hraw, meanb, rstdb, nullptr, nullptr, zknv_h, zknv_l);
    }

    // ---- phase 2: affinity + contrastive (B side = hi plane of zk_n) ----
    const int QA[3] = {1, 0, 0};
    const int QB[3] = {2, 2, 1};
    for (int v = 0; v < VNUM; ++v) {
        u16* zknv_h = zknh + (size_t)v * NR * FF;  u16* zknv_l = zknl + (size_t)v * NR * FF;
        u16* zqnv_h = zqnh + (size_t)v * NR * FF;  u16* zqnv_l = zqnl + (size_t)v * NR * FF;

        mgemm<4,0,0><<<dim3(NR/128, NR/128), TB, 0, stream>>>(zknv_h, zknv_l, zknv_h, nullptr, mp, nullptr, nullptr, nullptr, nullptr, NR, FF);
        affinity_rows<<<dim3(NR), TB, 0, stream>>>(mp, rowsum);

        mgemm<4,0,0><<<dim3(NR/128, NR/128), TB, 0, stream>>>(zqnv_h, zqnv_l, zknv_h, nullptr, sim, nullptr, nullptr, nullptr, nullptr, NR, FF);
        contrastive_rows<<<dim3(NR), TB, 0, stream>>>(sim, mp, rowsum, acc + 0);

        u16* pa_h = pnh + (size_t)QA[v] * NR * FF;  u16* pa_l = pnl + (size_t)QA[v] * NR * FF;
        mgemm<4,0,0><<<dim3(NR/128, NR/128), TB, 0, stream>>>(pa_h, pa_l, zknv_h, nullptr, sim, nullptr, nullptr, nullptr, nullptr, NR, FF);
        contrastive_rows<<<dim3(NR), TB, 0, stream>>>(sim, mp, rowsum, acc + 1);

        u16* pb_h = pnh + (size_t)QB[v] * NR * FF;  u16* pb_l = pnl + (size_t)QB[v] * NR * FF;
        mgemm<4,0,0><<<dim3(NR/128, NR/128), TB, 0, stream>>>(pb_h, pb_l, zknv_h, nullptr, sim, nullptr, nullptr, nullptr, nullptr, NR, FF);
        contrastive_rows<<<dim3(NR), TB, 0, stream>>>(sim, mp, rowsum, acc + 1);
    }

    finalize_k<<<dim3(1), dim3(1), 0, stream>>>(acc, out);
}

// Round 5
// 2665.853 us; speedup vs baseline: 4.2770x; 1.3578x over previous
//
#include <hip/hip_runtime.h>

#define NR 4096
#define DD 2048
#define HH 2048
#define FF 512
#define VNUM 3

typedef unsigned short u16;
typedef __attribute__((ext_vector_type(8))) short short8;
typedef __attribute__((ext_vector_type(4))) float f32x4;

// ---- bf16 helpers ----
__device__ __forceinline__ u16 f2bf(float f) {
    unsigned u = __float_as_uint(f);
    u += 0x7FFF + ((u >> 16) & 1);       // round-to-nearest-even
    return (u16)(u >> 16);
}
__device__ __forceinline__ float bf2f(u16 h) {
    return __uint_as_float((unsigned)h << 16);
}

__device__ __forceinline__ void gload16(const void* g, void* l) {
    __builtin_amdgcn_global_load_lds(
        (const __attribute__((address_space(1))) void*)g,
        (__attribute__((address_space(3))) void*)l, 16, 0, 0);
}

// ---------------------------------------------------------------------------
// Split-bf16 MFMA GEMM, 2-term: C = (Ah + Al) @ Bh.  BK=64 (half the barriers
// of round-4's BK=32).  A planes [M][K] bf16 hi+lo; B plane [N][K] bf16.
// LDS rows of 64 bf16 (128B); 8-slot XOR swizzle (slot ^= row&7), applied on
// the global source during staging and on the ds_read offset (same involution).
// STATS=1: accumulate column sum/sumsq into psum/psq (pre-zeroed; bn_finalize
// re-zeroes).  EPI: 0 = fp32 out (ldc stride), 1 = +bias,relu -> planes,
// 2 = +bias -> planes.
// ---------------------------------------------------------------------------
template<int NREP, int EPI, int STATS>
__global__ __launch_bounds__(256) void mgemm(
    const u16* __restrict__ Ah, const u16* __restrict__ Al,
    const u16* __restrict__ Bh,
    const float* __restrict__ bias,
    float* __restrict__ Cf, u16* __restrict__ Ch, u16* __restrict__ Cl,
    float* __restrict__ psum, float* __restrict__ psq,
    int N, int K, int ldc)
{
    constexpr int BN = NREP * 32;
    __shared__ u16 sAh[128 * 64];
    __shared__ u16 sAl[128 * 64];
    __shared__ u16 sBh[BN * 64];

    const int tid  = threadIdx.x;
    const int wid  = tid >> 6;
    const int lane = tid & 63;
    const int bm = blockIdx.y * 128;
    const int bn = blockIdx.x * BN;

    // staging decode: lane -> (row-in-8, pos); source slot = pos ^ lrow
    const int lrow  = lane >> 3;                 // 0..7
    const int gslot = (lane & 7) ^ lrow;         // swizzled source 16B-slot

    // fragment decode
    const int frow  = lane & 15;
    const int fslot = lane >> 4;                 // 0..3
    const int wm = wid >> 1, wn = wid & 1;

    f32x4 acc[4][NREP];
#pragma unroll
    for (int i = 0; i < 4; ++i)
#pragma unroll
        for (int j = 0; j < NREP; ++j)
#pragma unroll
            for (int r = 0; r < 4; ++r) acc[i][j][r] = 0.f;

    constexpr int NB    = BN / 8;          // B issues (8 rows each)
    constexpr int TOT   = 32 + NB;         // A: 2 planes x 16
    constexpr int PER_W = TOT / 4;

    for (int k0 = 0; k0 < K; k0 += 64) {
#pragma unroll
        for (int t = 0; t < PER_W; ++t) {
            int q = wid + 4 * t;           // wave-uniform
            const u16* gp;
            u16* lp;
            if (q < 32) {
                int pl = q >> 4, rb = q & 15;
                const u16* src = pl ? Al : Ah;
                gp = src + (size_t)(bm + rb * 8 + lrow) * K + k0 + gslot * 8;
                lp = (pl ? sAl : sAh) + rb * 512;
            } else {
                int rb = q - 32;
                gp = Bh + (size_t)(bn + rb * 8 + lrow) * K + k0 + gslot * 8;
                lp = sBh + rb * 512;
            }
            gload16(gp, lp);
        }
        __syncthreads();

        short8 bfr[2][NREP];
#pragma unroll
        for (int ks = 0; ks < 2; ++ks)
#pragma unroll
            for (int j = 0; j < NREP; ++j) {
                int rb = wn * (NREP * 16) + j * 16 + frow;
                bfr[ks][j] = *(const short8*)(sBh + rb * 64 + (((fslot + ks * 4) ^ (rb & 7)) * 8));
            }
#pragma unroll
        for (int i = 0; i < 4; ++i) {
            int ra = wm * 64 + i * 16 + frow;
            int sa0 = ra * 64 + (( fslot      ^ (ra & 7)) * 8);
            int sa1 = ra * 64 + (((fslot + 4) ^ (ra & 7)) * 8);
            short8 ah0 = *(const short8*)(sAh + sa0);
            short8 ah1 = *(const short8*)(sAh + sa1);
            short8 al0 = *(const short8*)(sAl + sa0);
            short8 al1 = *(const short8*)(sAl + sa1);
#pragma unroll
            for (int j = 0; j < NREP; ++j) {
                acc[i][j] = __builtin_amdgcn_mfma_f32_16x16x32_bf16(ah0, bfr[0][j], acc[i][j], 0, 0, 0);
                acc[i][j] = __builtin_amdgcn_mfma_f32_16x16x32_bf16(al0, bfr[0][j], acc[i][j], 0, 0, 0);
                acc[i][j] = __builtin_amdgcn_mfma_f32_16x16x32_bf16(ah1, bfr[1][j], acc[i][j], 0, 0, 0);
                acc[i][j] = __builtin_amdgcn_mfma_f32_16x16x32_bf16(al1, bfr[1][j], acc[i][j], 0, 0, 0);
            }
        }
        __syncthreads();
    }

    float sj[NREP], qj[NREP];
#pragma unroll
    for (int j = 0; j < NREP; ++j) { sj[j] = 0.f; qj[j] = 0.f; }

    // D mapping: col = lane&15, row = (lane>>4)*4 + r   [m89-verified]
#pragma unroll
    for (int i = 0; i < 4; ++i) {
#pragma unroll
        for (int j = 0; j < NREP; ++j) {
            int gc = bn + wn * (NREP * 16) + j * 16 + (lane & 15);
            float bv = (EPI >= 1) ? bias[gc] : 0.f;
#pragma unroll
            for (int r = 0; r < 4; ++r) {
                int gr = bm + wm * 64 + i * 16 + (lane >> 4) * 4 + r;
                float vv = acc[i][j][r];
                size_t idx = (size_t)gr * ldc + gc;
                if (EPI == 0) {
                    Cf[idx] = vv;
                    if (STATS) { sj[j] += vv; qj[j] = fmaf(vv, vv, qj[j]); }
                } else {
                    vv += bv;
                    if (EPI == 1) vv = fmaxf(vv, 0.f);
                    u16 h = f2bf(vv);
                    Ch[idx] = h;
                    Cl[idx] = f2bf(vv - bf2f(h));
                }
            }
        }
    }

    if constexpr (STATS) {
        __shared__ float sstat[2 * BN];
        for (int t = tid; t < 2 * BN; t += 256) sstat[t] = 0.f;
        __syncthreads();
#pragma unroll
        for (int j = 0; j < NREP; ++j) {
            float s = sj[j], q = qj[j];
            s += __shfl_xor(s, 16); q += __shfl_xor(q, 16);
            s += __shfl_xor(s, 32); q += __shfl_xor(q, 32);
            if ((lane >> 4) == 0) {
                int cl = wn * (NREP * 16) + j * 16 + (lane & 15);
                atomicAdd(&sstat[cl], s);
                atomicAdd(&sstat[BN + cl], q);
            }
        }
        __syncthreads();
        for (int t = tid; t < BN; t += 256) {
            atomicAdd(psum + bn + t, sstat[t]);
            atomicAdd(psq  + bn + t, sstat[BN + t]);
        }
    }
}

// ---------------------------------------------------------------------------
// 3-segment GEMM (M = 3 x 4096) with fused contrastive epilogue.
// sim = A_seg @ zk^T; s = 2*sim <= 2 (unit rows) -> fixed-max logsumexp:
// per row accumulate se = sum exp(s-2), dot = sum mp*s into per-(block,wave)
// partial slots [64][12288].  No sim materialization.
// ---------------------------------------------------------------------------
__global__ __launch_bounds__(256) void mgemm_ctr(
    const u16* __restrict__ Ah0, const u16* __restrict__ Al0,
    const u16* __restrict__ Ah1, const u16* __restrict__ Al1,
    const u16* __restrict__ Ah2, const u16* __restrict__ Al2,
    const u16* __restrict__ Bh,
    const float* __restrict__ mp,
    float* __restrict__ pse, float* __restrict__ pdot, int K)
{
    __shared__ u16 sAh[128 * 64];
    __shared__ u16 sAl[128 * 64];
    __shared__ u16 sBh[128 * 64];

    const int tid  = threadIdx.x;
    const int wid  = tid >> 6;
    const int lane = tid & 63;
    const int seg = blockIdx.y >> 5;
    const int bml = (blockIdx.y & 31) * 128;
    const int bn  = blockIdx.x * 128;
    const u16* Ah = (seg == 0) ? Ah0 : (seg == 1) ? Ah1 : Ah2;
    const u16* Al = (seg == 0) ? Al0 : (seg == 1) ? Al1 : Al2;

    const int lrow  = lane >> 3;
    const int gslot = (lane & 7) ^ lrow;
    const int frow  = lane & 15;
    const int fslot = lane >> 4;
    const int wm = wid >> 1, wn = wid & 1;

    f32x4 acc[4][4];
#pragma unroll
    for (int i = 0; i < 4; ++i)
#pragma unroll
        for (int j = 0; j < 4; ++j)
#pragma unroll
            for (int r = 0; r < 4; ++r) acc[i][j][r] = 0.f;

    for (int k0 = 0; k0 < K; k0 += 64) {
#pragma unroll
        for (int t = 0; t < 12; ++t) {
            int q = wid + 4 * t;
            const u16* gp;
            u16* lp;
            if (q < 32) {
                int pl = q >> 4, rb = q & 15;
                const u16* src = pl ? Al : Ah;
                gp = src + (size_t)(bml + rb * 8 + lrow) * K + k0 + gslot * 8;
                lp = (pl ? sAl : sAh) + rb * 512;
            } else {
                int rb = q - 32;
                gp = Bh + (size_t)(bn + rb * 8 + lrow) * K + k0 + gslot * 8;
                lp = sBh + rb * 512;
            }
            gload16(gp, lp);
        }
        __syncthreads();

        short8 bfr[2][4];
#pragma unroll
        for (int ks = 0; ks < 2; ++ks)
#pragma unroll
            for (int j = 0; j < 4; ++j) {
                int rb = wn * 64 + j * 16 + frow;
                bfr[ks][j] = *(const short8*)(sBh + rb * 64 + (((fslot + ks * 4) ^ (rb & 7)) * 8));
            }
#pragma unroll
        for (int i = 0; i < 4; ++i) {
            int ra = wm * 64 + i * 16 + frow;
            int sa0 = ra * 64 + (( fslot      ^ (ra & 7)) * 8);
            int sa1 = ra * 64 + (((fslot + 4) ^ (ra & 7)) * 8);
            short8 ah0 = *(const short8*)(sAh + sa0);
            short8 ah1 = *(const short8*)(sAh + sa1);
            short8 al0 = *(const short8*)(sAl + sa0);
            short8 al1 = *(const short8*)(sAl + sa1);
#pragma unroll
            for (int j = 0; j < 4; ++j) {
                acc[i][j] = __builtin_amdgcn_mfma_f32_16x16x32_bf16(ah0, bfr[0][j], acc[i][j], 0, 0, 0);
                acc[i][j] = __builtin_amdgcn_mfma_f32_16x16x32_bf16(al0, bfr[0][j], acc[i][j], 0, 0, 0);
                acc[i][j] = __builtin_amdgcn_mfma_f32_16x16x32_bf16(ah1, bfr[1][j], acc[i][j], 0, 0, 0);
                acc[i][j] = __builtin_amdgcn_mfma_f32_16x16x32_bf16(al1, bfr[1][j], acc[i][j], 0, 0, 0);
            }
        }
        __syncthreads();
    }

    // fused contrastive epilogue
#pragma unroll
    for (int i = 0; i < 4; ++i) {
        float se0 = 0.f, se1 = 0.f, se2 = 0.f, se3 = 0.f;
        float d0 = 0.f, d1 = 0.f, d2 = 0.f, d3 = 0.f;
        int rbase = bml + wm * 64 + i * 16 + (lane >> 4) * 4;  // local q-row
#pragma unroll
        for (int j = 0; j < 4; ++j) {
            int gc = bn + wn * 64 + j * 16 + (lane & 15);
            const float* mpp = mp + (size_t)rbase * NR + gc;
            float s0 = 2.f * acc[i][j][0];
            float s1 = 2.f * acc[i][j][1];
            float s2 = 2.f * acc[i][j][2];
            float s3 = 2.f * acc[i][j][3];
            se0 += __expf(s0 - 2.f); d0 = fmaf(mpp[0],            s0, d0);
            se1 += __expf(s1 - 2.f); d1 = fmaf(mpp[(size_t)NR],   s1, d1);
            se2 += __expf(s2 - 2.f); d2 = fmaf(mpp[(size_t)2*NR], s2, d2);
            se3 += __expf(s3 - 2.f); d3 = fmaf(mpp[(size_t)3*NR], s3, d3);
        }
#pragma unroll
        for (int o = 1; o < 16; o <<= 1) {
            se0 += __shfl_xor(se0, o); se1 += __shfl_xor(se1, o);
            se2 += __shfl_xor(se2, o); se3 += __shfl_xor(se3, o);
            d0  += __shfl_xor(d0, o);  d1  += __shfl_xor(d1, o);
            d2  += __shfl_xor(d2, o);  d3  += __shfl_xor(d3, o);
        }
        if ((lane & 15) == 0) {
            int slot = blockIdx.x * 2 + wn;
            size_t base = (size_t)slot * (3 * NR) + seg * NR + rbase;
            pse[base + 0] = se0; pse[base + 1] = se1;
            pse[base + 2] = se2; pse[base + 3] = se3;
            pdot[base + 0] = d0; pdot[base + 1] = d1;
            pdot[base + 2] = d2; pdot[base + 3] = d3;
        }
    }
}

// reduce 64 partial slots per row; contrib = lse - dot/rowsum; sum into acc
__global__ __launch_bounds__(256) void ctr_finalize(
    const float* __restrict__ pse, const float* __restrict__ pdot,
    const float* __restrict__ rowsum, double* __restrict__ acc)
{
    int row = blockIdx.x * 256 + threadIdx.x;   // 0..12287
    float se = 0.f, dt = 0.f;
    for (int s = 0; s < 64; ++s) {
        se += pse[(size_t)s * (3 * NR) + row];
        dt += pdot[(size_t)s * (3 * NR) + row];
    }
    float rs = rowsum[row & (NR - 1)];
    double contrib = (double)(2.f + logf(se)) - (double)dt / (double)rs;
    __shared__ double sd[256];
    sd[threadIdx.x] = contrib;
    __syncthreads();
    for (int o = 128; o > 0; o >>= 1) {
        if (threadIdx.x < o) sd[threadIdx.x] += sd[threadIdx.x + o];
        __syncthreads();
    }
    if (threadIdx.x == 0) atomicAdd(blockIdx.x < 16 ? acc : acc + 1, sd[0]);
}

// ---------------------------------------------------------------------------
// Weight transpose + bf16 round (+ optional EMA blend): [K][N] fp32 -> [N][K]
// ---------------------------------------------------------------------------
template<int EMA>
__global__ __launch_bounds__(256) void transpose_split(
    const float* __restrict__ Wm, const float* __restrict__ W2,
    const float* __restrict__ mom,
    u16* __restrict__ oh, int K, int N)
{
    __shared__ float t[32][33];
    const int tx = threadIdx.x & 31, ty = threadIdx.x >> 5;
    const int bx = blockIdx.x * 32;   // N dir
    const int by = blockIdx.y * 32;   // K dir
    float m = 0.f, m1 = 0.f;
    if (EMA) { m = mom[0]; m1 = 1.f - m; }
#pragma unroll
    for (int r = 0; r < 32; r += 8) {
        size_t gi = (size_t)(by + ty + r) * N + bx + tx;
        float v = Wm[gi];
        if (EMA) v = m * v + m1 * W2[gi];
        t[ty + r][tx] = v;
    }
    __syncthreads();
#pragma unroll
    for (int r = 0; r < 32; r += 8) {
        float v = t[tx][ty + r];
        oh[(size_t)(bx + ty + r) * K + by + tx] = f2bf(v);
    }
}

// ---------------------------------------------------------------------------
__global__ void convert_split(const float* __restrict__ X,
                              u16* __restrict__ oh, u16* __restrict__ ol, int total4)
{
    int stride = gridDim.x * blockDim.x;
    for (int t = blockIdx.x * blockDim.x + threadIdx.x; t < total4; t += stride) {
        float4 v = ((const float4*)X)[t];
        ushort4 vh, vl;
        vh.x = f2bf(v.x); vl.x = f2bf(v.x - bf2f(vh.x));
        vh.y = f2bf(v.y); vl.y = f2bf(v.y - bf2f(vh.y));
        vh.z = f2bf(v.z); vl.z = f2bf(v.z - bf2f(vh.z));
        vh.w = f2bf(v.w); vl.w = f2bf(v.w - bf2f(vh.w));
        ((ushort4*)oh)[t] = vh;
        ((ushort4*)ol)[t] = vl;
    }
}

// ---------------------------------------------------------------------------
__global__ void bn_finalize(float* __restrict__ psum, float* __restrict__ psq,
                            float* __restrict__ meanb, float* __restrict__ rstdb)
{
    int c = blockIdx.x * 256 + threadIdx.x;
    float s = psum[c], q = psq[c];
    psum[c] = 0.f; psq[c] = 0.f;
    float mn  = s * (1.0f / NR);
    float var = q * (1.0f / NR) - mn * mn;
    meanb[c] = mn;
    rstdb[c] = rsqrtf(var + 1e-5f);
}

// BN apply (C=2048-wide planes) from strided raw matrix X[row*ldx + coff + c].
// MODE 1: relu(affine); MODE 2: relu(EMA-blended affine). meanb/rstdb pre-offset.
template<int MODE>
__global__ void bn_apply_p(const float* __restrict__ X,
                           const float* __restrict__ meanb, const float* __restrict__ rstdb,
                           const float* __restrict__ ga, const float* __restrict__ ba,
                           const float* __restrict__ gb, const float* __restrict__ bb,
                           const float* __restrict__ mom,
                           u16* __restrict__ oh, u16* __restrict__ ol,
                           int total4, int ldx, int coff)
{
    float m = 0.f, m1 = 0.f;
    if (MODE == 2) { m = mom[0]; m1 = 1.f - m; }
    int stride = gridDim.x * blockDim.x;
    for (int t = blockIdx.x * blockDim.x + threadIdx.x; t < total4; t += stride) {
        int t4 = t << 2;
        int row = t4 >> 11;            // C = 2048 fixed
        int c = t4 & 2047;
        float4 v  = *(const float4*)(X + (size_t)row * ldx + coff + c);
        float4 mn = *(const float4*)(meanb + c);
        float4 rs = *(const float4*)(rstdb + c);
        v.x = (v.x - mn.x) * rs.x; v.y = (v.y - mn.y) * rs.y;
        v.z = (v.z - mn.z) * rs.z; v.w = (v.w - mn.w) * rs.w;
        float4 gg  = *(const float4*)(ga + c);
        float4 bbv = *(const float4*)(ba + c);
        if (MODE == 2) {
            float4 g2 = *(const float4*)(gb + c);
            float4 b2 = *(const float4*)(bb + c);
            gg.x  = m*gg.x  + m1*g2.x; gg.y  = m*gg.y  + m1*g2.y;
            gg.z  = m*gg.z  + m1*g2.z; gg.w  = m*gg.w  + m1*g2.w;
            bbv.x = m*bbv.x + m1*b2.x; bbv.y = m*bbv.y + m1*b2.y;
            bbv.z = m*bbv.z + m1*b2.z; bbv.w = m*bbv.w + m1*b2.w;
        }
        v.x = fmaxf(fmaf(v.x, gg.x, bbv.x), 0.f);
        v.y = fmaxf(fmaf(v.y, gg.y, bbv.y), 0.f);
        v.z = fmaxf(fmaf(v.z, gg.z, bbv.z), 0.f);
        v.w = fmaxf(fmaf(v.w, gg.w, bbv.w), 0.f);
        ushort4 vh, vl;
        vh.x = f2bf(v.x); vl.x = f2bf(v.x - bf2f(vh.x));
        vh.y = f2bf(v.y); vl.y = f2bf(v.y - bf2f(vh.y));
        vh.z = f2bf(v.z); vl.z = f2bf(v.z - bf2f(vh.z));
        vh.w = f2bf(v.w); vl.w = f2bf(v.w - bf2f(vh.w));
        ((ushort4*)oh)[t] = vh;
        ((ushort4*)ol)[t] = vl;
    }
}

// ---------------------------------------------------------------------------
// Fused BN(no-affine) + row L2-normalize (F=512 outputs, strided input).
// ---------------------------------------------------------------------------
template<int WRITE_RAW>
__global__ void bn_l2_rows(const float* __restrict__ X,
                           const float* __restrict__ meanb, const float* __restrict__ rstdb,
                           u16* __restrict__ rh, u16* __restrict__ rl,
                           u16* __restrict__ onh, u16* __restrict__ onl, int ldx)
{
    const int row = blockIdx.x;
    const int lane = threadIdx.x;   // 64
    const int c0 = lane * 8;
    const float4* xr  = (const float4*)(X + (size_t)row * ldx + c0);
    const float4* mnp = (const float4*)(meanb + c0);
    const float4* rsp = (const float4*)(rstdb + c0);
    float4 v0 = xr[0], v1 = xr[1];
    float4 m0 = mnp[0], m1 = mnp[1];
    float4 r0 = rsp[0], r1 = rsp[1];
    float f[8];
    f[0] = (v0.x - m0.x) * r0.x; f[1] = (v0.y - m0.y) * r0.y;
    f[2] = (v0.z - m0.z) * r0.z; f[3] = (v0.w - m0.w) * r0.w;
    f[4] = (v1.x - m1.x) * r1.x; f[5] = (v1.y - m1.y) * r1.y;
    f[6] = (v1.z - m1.z) * r1.z; f[7] = (v1.w - m1.w) * r1.w;
    if (WRITE_RAW) {
        ushort4 h0, l0, h1, l1;
        h0.x = f2bf(f[0]); l0.x = f2bf(f[0] - bf2f(h0.x));
        h0.y = f2bf(f[1]); l0.y = f2bf(f[1] - bf2f(h0.y));
        h0.z = f2bf(f[2]); l0.z = f2bf(f[2] - bf2f(h0.z));
        h0.w = f2bf(f[3]); l0.w = f2bf(f[3] - bf2f(h0.w));
        h1.x = f2bf(f[4]); l1.x = f2bf(f[4] - bf2f(h1.x));
        h1.y = f2bf(f[5]); l1.y = f2bf(f[5] - bf2f(h1.y));
        h1.z = f2bf(f[6]); l1.z = f2bf(f[6] - bf2f(h1.z));
        h1.w = f2bf(f[7]); l1.w = f2bf(f[7] - bf2f(h1.w));
        ushort4* ph = (ushort4*)(rh + (size_t)row * FF + c0);
        ushort4* pl = (ushort4*)(rl + (size_t)row * FF + c0);
        ph[0] = h0; ph[1] = h1;
        pl[0] = l0; pl[1] = l1;
    }
    float ss = 0.f;
#pragma unroll
    for (int j = 0; j < 8; ++j) ss = fmaf(f[j], f[j], ss);
#pragma unroll
    for (int o = 32; o > 0; o >>= 1) ss += __shfl_xor(ss, o);
    float sc = 1.f / fmaxf(sqrtf(ss), 1e-12f);
    ushort4 nh0, nl0, nh1, nl1;
    float y;
    y = f[0] * sc; nh0.x = f2bf(y); nl0.x = f2bf(y - bf2f(nh0.x));
    y = f[1] * sc; nh0.y = f2bf(y); nl0.y = f2bf(y - bf2f(nh0.y));
    y = f[2] * sc; nh0.z = f2bf(y); nl0.z = f2bf(y - bf2f(nh0.z));
    y = f[3] * sc; nh0.w = f2bf(y); nl0.w = f2bf(y - bf2f(nh0.w));
    y = f[4] * sc; nh1.x = f2bf(y); nl1.x = f2bf(y - bf2f(nh1.x));
    y = f[5] * sc; nh1.y = f2bf(y); nl1.y = f2bf(y - bf2f(nh1.y));
    y = f[6] * sc; nh1.z = f2bf(y); nl1.z = f2bf(y - bf2f(nh1.z));
    y = f[7] * sc; nh1.w = f2bf(y); nl1.w = f2bf(y - bf2f(nh1.w));
    ushort4* qh = (ushort4*)(onh + (size_t)row * FF + c0);
    ushort4* ql = (ushort4*)(onl + (size_t)row * FF + c0);
    qh[0] = nh0; qh[1] = nh1;
    ql[0] = nl0; ql[1] = nl1;
}

// ---------------------------------------------------------------------------
__global__ void l2norm_p(const u16* __restrict__ ih, const u16* __restrict__ il,
                         u16* __restrict__ oh, u16* __restrict__ ol)
{
    const int row = blockIdx.x;
    const int lane = threadIdx.x;   // 64
    const short8* ph = (const short8*)(ih + (size_t)row * FF);
    const short8* pl = (const short8*)(il + (size_t)row * FF);
    short8 vh = ph[lane];
    short8 vl = pl[lane];
    float f[8];
    float ss = 0.f;
#pragma unroll
    for (int j = 0; j < 8; ++j) {
        f[j] = bf2f((u16)vh[j]) + bf2f((u16)vl[j]);
        ss = fmaf(f[j], f[j], ss);
    }
#pragma unroll
    for (int o = 32; o > 0; o >>= 1) ss += __shfl_xor(ss, o);
    float sc = 1.f / fmaxf(sqrtf(ss), 1e-12f);
    short8 rh, rl;
#pragma unroll
    for (int j = 0; j < 8; ++j) {
        float y = f[j] * sc;
        u16 h = f2bf(y);
        rh[j] = (short)h;
        rl[j] = (short)f2bf(y - bf2f(h));
    }
    ((short8*)(oh + (size_t)row * FF))[lane] = rh;
    ((short8*)(ol + (size_t)row * FF))[lane] = rl;
}

// ---------------------------------------------------------------------------
__device__ __forceinline__ float block_sum(float v, float* sred)
{
#pragma unroll
    for (int o = 32; o > 0; o >>= 1) v += __shfl_xor(v, o);
    __syncthreads();
    if ((threadIdx.x & 63) == 0) sred[threadIdx.x >> 6] = v;
    __syncthreads();
    return sred[0] + sred[1] + sred[2] + sred[3];
}

// ---------------------------------------------------------------------------
// kernel_affinity row transform (in place over S = zk_n @ zk_n^T)
// ---------------------------------------------------------------------------
__global__ __launch_bounds__(256) void affinity_rows(float* __restrict__ S,
                                                     float* __restrict__ rowsum)
{
    const int i = blockIdx.x;
    const int tid = threadIdx.x;
    __shared__ float arow[NR];
    __shared__ float sred[4];
    __shared__ float svv[4];
    __shared__ int   sii[4];
    float* Srow = S + (size_t)i * NR;

    float s1 = 0.f;
    for (int j = tid; j < NR; j += 256) {
        float sij = Srow[j];
        float d = fmaxf(2.f - 2.f * sij, 0.f);
        float a = expf(-10.f * d);
        arow[j] = a;
        s1 += a;
    }
    __syncthreads();
    float S1 = block_sum(s1, sred);
    float invS1 = 1.f / S1;
    float Ad = arow[i] * invS1;
    __syncthreads();

    float s2 = 0.f;
    float bv = 3.4e38f; int bi = NR;
    for (int j = tid; j < NR; j += 256) {
        float Aj = arow[j] * invS1;
        arow[j] = Aj;
        float diff = fabsf(Ad - Aj);
        float key = diff + (j == i ? 1.f : 0.f);
        if (key < bv) { bv = key; bi = j; }
        s2 += (j == i) ? 0.f : expf(Aj);
    }
    float S2 = block_sum(s2, sred);

#pragma unroll
    for (int o = 32; o > 0; o >>= 1) {
        float ov = __shfl_xor(bv, o);
        int   oi = __shfl_xor(bi, o);
        if (ov < bv || (ov == bv && oi < bi)) { bv = ov; bi = oi; }
    }
    __syncthreads();
    if ((tid & 63) == 0) { svv[tid >> 6] = bv; sii[tid >> 6] = bi; }
    __syncthreads();
    float fv = svv[0]; int idx = sii[0];
#pragma unroll
    for (int u = 1; u < 4; ++u)
        if (svv[u] < fv || (svv[u] == fv && sii[u] < idx)) { fv = svv[u]; idx = sii[u]; }

    float invS2 = 1.f / S2;
    float s3 = 0.f;
    for (int j = tid; j < NR; j += 256) {
        float Aj = arow[j];
        float diff = fabsf(Ad - Aj);
        float thr = (diff < 0.8f) ? 1.f : 0.f;
        float ind = ((j == idx) ? 1.f : 0.f) + ((j == i) ? 1.f : 0.f);
        float tk = thr * ind;
        float E = (j == i) ? 0.f : expf(Aj);
        float w = 1.f - E * invS2;
        float dyn = tk * w + (1.f - tk);
        float mv2 = Aj * dyn;
        Srow[j] = mv2;
        s3 += mv2;
    }
    float S3 = block_sum(s3, sred);
    if (tid == 0) rowsum[i] = S3;
}

__global__ void finalize_k(const double* __restrict__ acc, float* __restrict__ out)
{
    const double nn = (double)NR * (double)NR;
    out[0] = (float)(acc[0] / (3.0 * nn) + acc[1] / (6.0 * nn));
}

// ---------------------------------------------------------------------------
extern "C" void kernel_launch(void* const* d_in, const int* in_sizes, int n_in,
                              void* d_out, int out_size, void* d_ws, size_t ws_size,
                              hipStream_t stream)
{
    const float* x   = (const float*)d_in[0];
    const float* W1  = (const float*)d_in[1];
    const float* g1  = (const float*)d_in[2];
    const float* b1  = (const float*)d_in[3];
    const float* W2  = (const float*)d_in[4];
    const float* g2  = (const float*)d_in[5];
    const float* b2  = (const float*)d_in[6];
    const float* W3  = (const float*)d_in[7];
    const float* tW1 = (const float*)d_in[8];
    const float* tg1 = (const float*)d_in[9];
    const float* tb1 = (const float*)d_in[10];
    const float* tW2 = (const float*)d_in[11];
    const float* tg2 = (const float*)d_in[12];
    const float* tb2 = (const float*)d_in[13];
    const float* tW3 = (const float*)d_in[14];
    const float* dW1 = (const float*)d_in[15];
    const float* db1 = (const float*)d_in[16];
    const float* dW2 = (const float*)d_in[17];
    const float* db2 = (const float*)d_in[18];
    const float* mom = (const float*)d_in[19];
    float* out = (float*)d_out;

    // ---- workspace carve (~234 MB). hraw (64MB, phase-1) aliases mp (phase-2).
    char* base = (char*)d_ws;
    size_t off = 0;
    auto take = [&](size_t b) { void* p = base + off; off += (b + 255) & ~(size_t)255; return p; };
    u16* xph  = (u16*)take((size_t)NR * DD * 2);            // 16MB
    u16* xpl  = (u16*)take((size_t)NR * DD * 2);            // 16MB
    u16* wth  = (u16*)take((size_t)2 * HH * DD * 2);        // 16MB ([4096][2048] max)
    float* hraw = (float*)take((size_t)NR * 2 * HH * 4);    // 64MB [4096][4096]
    float* mp   = hraw;                                     // phase-2 alias
    u16* hph  = (u16*)take((size_t)NR * HH * 2);
    u16* hpl  = (u16*)take((size_t)NR * HH * 2);
    u16* zrph = (u16*)take((size_t)NR * FF * 2);
    u16* zrpl = (u16*)take((size_t)NR * FF * 2);
    u16* zqnh = (u16*)take((size_t)VNUM * NR * FF * 2);
    u16* zqnl = (u16*)take((size_t)VNUM * NR * FF * 2);
    u16* zknh = (u16*)take((size_t)VNUM * NR * FF * 2);
    u16* zknl = (u16*)take((size_t)VNUM * NR * FF * 2);
    u16* pnh  = (u16*)take((size_t)VNUM * NR * FF * 2);
    u16* pnl  = (u16*)take((size_t)VNUM * NR * FF * 2);
    float* pse  = (float*)take((size_t)64 * 3 * NR * 4);    // 3.15MB
    float* pdot = (float*)take((size_t)64 * 3 * NR * 4);    // 3.15MB
    float* rowsum = (float*)take((size_t)NR * 4);
    float* psum   = (float*)take((size_t)2 * HH * 4);       // 4096 cols
    float* psq    = (float*)take((size_t)2 * HH * 4);
    float* meanb  = (float*)take((size_t)2 * HH * 4);
    float* rstdb  = (float*)take((size_t)2 * HH * 4);
    double* acc   = (double*)take(256);

    hipMemsetAsync(acc, 0, 2 * sizeof(double), stream);
    hipMemsetAsync(psum, 0, (size_t)4 * HH * 4, stream);    // psum+psq (adjacent)

    const dim3 TB(256);

    for (int v = 0; v < VNUM; ++v) {
        const float* xv = x + (size_t)v * NR * DD;
        const float* W1v  = W1  + (size_t)v * DD * HH;
        const float* W2v  = W2  + (size_t)v * HH * HH;
        const float* W3v  = W3  + (size_t)v * HH * FF;
        const float* tW1v = tW1 + (size_t)v * DD * HH;
        const float* tW2v = tW2 + (size_t)v * HH * HH;
        const float* tW3v = tW3 + (size_t)v * HH * FF;
        const float* dW1v = dW1 + (size_t)v * FF * HH;
        const float* dW2v = dW2 + (size_t)v * HH * FF;
        const float* g1v = g1 + (size_t)v * HH;   const float* b1v = b1 + (size_t)v * HH;
        const float* g2v = g2 + (size_t)v * HH;   const float* b2v = b2 + (size_t)v * HH;
        const float* tg1v = tg1 + (size_t)v * HH; const float* tb1v = tb1 + (size_t)v * HH;
        const float* tg2v = tg2 + (size_t)v * HH; const float* tb2v = tb2 + (size_t)v * HH;
        const float* db1v = db1 + (size_t)v * HH;
        const float* db2v = db2 + (size_t)v * FF;
        u16* zqnv_h = zqnh + (size_t)v * NR * FF;  u16* zqnv_l = zqnl + (size_t)v * NR * FF;
        u16* zknv_h = zknh + (size_t)v * NR * FF;  u16* zknv_l = zknl + (size_t)v * NR * FF;
        u16* pnv_h  = pnh  + (size_t)v * NR * FF;  u16* pnv_l  = pnl  + (size_t)v * NR * FF;

        convert_split<<<dim3(2048), TB, 0, stream>>>(xv, xph, xpl, NR * DD / 4);

        // ---- fused layer-1 (online cols 0-2047 | target cols 2048-4095) ----
        transpose_split<0><<<dim3(HH/32, DD/32), TB, 0, stream>>>(W1v, nullptr, nullptr, wth, DD, HH);
        transpose_split<1><<<dim3(HH/32, DD/32), TB, 0, stream>>>(tW1v, W1v, mom, wth + (size_t)HH * DD, DD, HH);
        mgemm<4,0,1><<<dim3(2*HH/128, NR/128), TB, 0, stream>>>(xph, xpl, wth, nullptr, hraw, nullptr, nullptr, psum, psq, 2*HH, DD, 2*HH);
        bn_finalize<<<dim3(2*HH/256), TB, 0, stream>>>(psum, psq, meanb, rstdb);

        // ---- online path ----
        bn_apply_p<1><<<dim3(2048), TB, 0, stream>>>(hraw, meanb, rstdb, g1v, b1v, nullptr, nullptr, nullptr, hph, hpl, NR*HH/4, 2*HH, 0);
        transpose_split<0><<<dim3(HH/32, HH/32), TB, 0, stream>>>(W2v, nullptr, nullptr, wth, HH, HH);
        mgemm<4,0,1><<<dim3(HH/128, NR/128), TB, 0, stream>>>(hph, hpl, wth, nullptr, hraw, nullptr, nullptr, psum, psq, HH, HH, 2*HH);
        bn_finalize<<<dim3(HH/256), TB, 0, stream>>>(psum, psq, meanb, rstdb);
        bn_apply_p<1><<<dim3(2048), TB, 0, stream>>>(hraw, meanb, rstdb, g2v, b2v, nullptr, nullptr, nullptr, hph, hpl, NR*HH/4, 2*HH, 0);

        transpose_split<0><<<dim3(FF/32, HH/32), TB, 0, stream>>>(W3v, nullptr, nullptr, wth, HH, FF);
        mgemm<2,0,1><<<dim3(FF/64, NR/128), TB, 0, stream>>>(hph, hpl, wth, nullptr, hraw, nullptr, nullptr, psum, psq, FF, HH, 2*HH);
        bn_finalize<<<dim3(FF/256), TB, 0, stream>>>(psum, psq, meanb, rstdb);
        bn_l2_rows<1><<<dim3(NR), dim3(64), 0, stream>>>(hraw, meanb, rstdb, zrph, zrpl, zqnv_h, zqnv_l, 2*HH);

        // ---- mlp -> p ----
        transpose_split<0><<<dim3(HH/32, FF/32), TB, 0, stream>>>(dW1v, nullptr, nullptr, wth, FF, HH);
        mgemm<4,1,0><<<dim3(HH/128, NR/128), TB, 0, stream>>>(zrph, zrpl, wth, db1v, nullptr, hph, hpl, nullptr, nullptr, HH, FF, HH);
        transpose_split<0><<<dim3(FF/32, HH/32), TB, 0, stream>>>(dW2v, nullptr, nullptr, wth, HH, FF);
        mgemm<2,2,0><<<dim3(FF/64, NR/128), TB, 0, stream>>>(hph, hpl, wth, db2v, nullptr, zrph, zrpl, nullptr, nullptr, FF, HH, FF);
        l2norm_p<<<dim3(NR), dim3(64), 0, stream>>>(zrph, zrpl, pnv_h, pnv_l);

        // ---- target path (L1 stats at cols 2048+ untouched by the above) ----
        bn_apply_p<2><<<dim3(2048), TB, 0, stream>>>(hraw, meanb + HH, rstdb + HH, tg1v, tb1v, g1v, b1v, mom, hph, hpl, NR*HH/4, 2*HH, HH);
        transpose_split<1><<<dim3(HH/32, HH/32), TB, 0, stream>>>(tW2v, W2v, mom, wth, HH, HH);
        mgemm<4,0,1><<<dim3(HH/128, NR/128), TB, 0, stream>>>(hph, hpl, wth, nullptr, hraw, nullptr, nullptr, psum, psq, HH, HH, 2*HH);
        bn_finalize<<<dim3(HH/256), TB, 0, stream>>>(psum, psq, meanb, rstdb);
        bn_apply_p<2><<<dim3(2048), TB, 0, stream>>>(hraw, meanb, rstdb, tg2v, tb2v, g2v, b2v, mom, hph, hpl, NR*HH/4, 2*HH, 0);

        transpose_split<1><<<dim3(FF/32, HH/32), TB, 0, stream>>>(tW3v, W3v, mom, wth, HH, FF);
        mgemm<2,0,1><<<dim3(FF/64, NR/128), TB, 0, stream>>>(hph, hpl, wth, nullptr, hraw, nullptr, nullptr, psum, psq, FF, HH, 2*HH);
        bn_finalize<<<dim3(FF/256), TB, 0, stream>>>(psum, psq, meanb, rstdb);
        bn_l2_rows<0><<<dim3(NR), dim3(64), 0, stream>>>(hraw, meanb, rstdb, nullptr, nullptr, zknv_h, zknv_l, 2*HH);
    }

    // ---- phase 2: affinity + fused contrastive ----
    const int QA[3] = {1, 0, 0};
    const int QB[3] = {2, 2, 1};
    for (int v = 0; v < VNUM; ++v) {
        u16* zknv_h = zknh + (size_t)v * NR * FF;  u16* zknv_l = zknl + (size_t)v * NR * FF;
        u16* zqnv_h = zqnh + (size_t)v * NR * FF;  u16* zqnv_l = zqnl + (size_t)v * NR * FF;
        u16* pa_h = pnh + (size_t)QA[v] * NR * FF;  u16* pa_l = pnl + (size_t)QA[v] * NR * FF;
        u16* pb_h = pnh + (size_t)QB[v] * NR * FF;  u16* pb_l = pnl + (size_t)QB[v] * NR * FF;

        mgemm<4,0,0><<<dim3(NR/128, NR/128), TB, 0, stream>>>(zknv_h, zknv_l, zknv_h, nullptr, mp, nullptr, nullptr, nullptr, nullptr, NR, FF, NR);
        affinity_rows<<<dim3(NR), TB, 0, stream>>>(mp, rowsum);

        mgemm_ctr<<<dim3(NR/128, 3 * NR/128), TB, 0, stream>>>(
            zqnv_h, zqnv_l, pa_h, pa_l, pb_h, pb_l, zknv_h, mp, pse, pdot, FF);
        ctr_finalize<<<dim3(3 * NR / 256), TB, 0, stream>>>(pse, pdot, rowsum, acc);
    }

    finalize_k<<<dim3(1), dim3(1), 0, stream>>>(acc, out);
}